// Round 4
// baseline (3391.187 us; speedup 1.0000x reference)
//
#include <hip/hip_runtime.h>
#include <math.h>

#define LPAD  10240
#define NSEQ  10001
#define PADT  239
#define NPIX  10000

typedef unsigned short u16;
typedef __attribute__((ext_vector_type(8))) short short8;
typedef __attribute__((ext_vector_type(4))) float floatx4;

__device__ __forceinline__ float b2f(u16 u){ return __uint_as_float(((unsigned)u)<<16); }
__device__ __forceinline__ u16 f2b(float f){
    unsigned x = __float_as_uint(f);
    return (u16)((x + 0x7FFFu + ((x>>16)&1u)) >> 16);
}
__device__ __forceinline__ void gld16(const void* g, void* l){
    __builtin_amdgcn_global_load_lds(
        (const __attribute__((address_space(1))) unsigned int*)g,
        (__attribute__((address_space(3))) unsigned int*)l, 16, 0, 0);
}

// ---------------------------------------------------------------------------
// bf16 MFMA GEMM: C = A @ Bt^T (+bias)(+resid)(relu)(qscale). A: M x K bf16
// row-major (lda, batch sA). Bt: N x K bf16 (ldb, sB). C fp32 or bf16 (obf16),
// 128x128 tile, 4 waves, 16x16x32 MFMA, global_load_lds width-16 staging.
// ---------------------------------------------------------------------------
__global__ __launch_bounds__(256) void gemm_mfma(
    const u16* __restrict__ A, int lda, long sA,
    const u16* __restrict__ Bt, int ldb, long sB,
    void* __restrict__ Cv, int ldc, long sC,
    int M, int N, int K, int ksplit,
    const float* __restrict__ bias,
    const float* __restrict__ resid, int ldr,
    int relu, int qscale, int obf16, int atomic)
{
    __shared__ u16 As[128*32];
    __shared__ u16 Bs[128*32];

    int bz = blockIdx.z / ksplit;
    int ks = blockIdx.z - bz * ksplit;
    A  += (size_t)bz * sA;
    Bt += (size_t)bz * sB;

    int kchunk = (K + ksplit - 1) / ksplit;
    kchunk = (kchunk + 31) & ~31;
    int kbeg = ks * kchunk;
    int kend = kbeg + kchunk; if (kend > K) kend = K;

    int tid = threadIdx.x;
    int w = tid >> 6, lane = tid & 63;
    int wm = (w >> 1) * 64, wn = (w & 1) * 64;
    int m0 = blockIdx.y * 128, n0 = blockIdx.x * 128;

    int l4 = lane >> 2;
    int lk = (lane & 3) * 8;
    int r0 = w * 32 + l4;
    int am0 = m0 + r0;      if (am0 > M-1) am0 = M-1;
    int am1 = m0 + r0 + 16; if (am1 > M-1) am1 = M-1;
    int bn0 = n0 + r0;      if (bn0 > N-1) bn0 = N-1;
    int bn1 = n0 + r0 + 16; if (bn1 > N-1) bn1 = N-1;
    const u16* ag0 = A  + (size_t)am0 * lda + lk;
    const u16* ag1 = A  + (size_t)am1 * lda + lk;
    const u16* bg0 = Bt + (size_t)bn0 * ldb + lk;
    const u16* bg1 = Bt + (size_t)bn1 * ldb + lk;
    u16* al0 = &As[(w*32)      * 32];
    u16* al1 = &As[(w*32 + 16) * 32];
    u16* bl0 = &Bs[(w*32)      * 32];
    u16* bl1 = &Bs[(w*32 + 16) * 32];

    floatx4 acc[4][4];
    #pragma unroll
    for (int i = 0; i < 4; i++)
        #pragma unroll
        for (int j = 0; j < 4; j++)
            acc[i][j] = (floatx4){0.f, 0.f, 0.f, 0.f};

    int arow = wm + (lane & 15);
    int nrow = wn + (lane & 15);
    int koff = (lane >> 4) * 8;

    for (int k0 = kbeg; k0 < kend; k0 += 32) {
        gld16(ag0 + k0, al0);
        gld16(ag1 + k0, al1);
        gld16(bg0 + k0, bl0);
        gld16(bg1 + k0, bl1);
        __syncthreads();
        short8 af[4], bf[4];
        #pragma unroll
        for (int i = 0; i < 4; i++) af[i] = *(const short8*)&As[(arow + i*16)*32 + koff];
        #pragma unroll
        for (int j = 0; j < 4; j++) bf[j] = *(const short8*)&Bs[(nrow + j*16)*32 + koff];
        #pragma unroll
        for (int i = 0; i < 4; i++)
            #pragma unroll
            for (int j = 0; j < 4; j++)
                acc[i][j] = __builtin_amdgcn_mfma_f32_16x16x32_bf16(af[i], bf[j], acc[i][j], 0, 0, 0);
        __syncthreads();
    }

    float* Cf = (float*)Cv;
    u16*   Ch = (u16*)Cv;
    size_t cb = (size_t)bz * sC;
    int rbase = m0 + wm + (lane >> 4) * 4;
    int cbase = n0 + wn + (lane & 15);
    #pragma unroll
    for (int i = 0; i < 4; i++) {
        #pragma unroll
        for (int j = 0; j < 4; j++) {
            int col = cbase + j * 16;
            if (col >= N) continue;
            float bcol = bias ? bias[col] : 0.f;
            #pragma unroll
            for (int r = 0; r < 4; r++) {
                int row = rbase + i * 16 + r;
                if (row >= M) continue;
                float v = acc[i][j][r];
                if (qscale && col < 512) v *= 0.125f;
                v += bcol;
                if (resid) v += resid[(size_t)row * ldr + col];
                if (relu) v = fmaxf(v, 0.f);
                size_t ci = cb + (size_t)row * ldc + col;
                if (obf16) Ch[ci] = f2b(v);
                else if (atomic) atomicAdd(&Cf[ci], v);
                else Cf[ci] = v;
            }
        }
    }
}

// ---------------------------------------------------------------------------
// Newton-Schulz MFMA gemm: 256x256x256, batch 8 (grid 2,2,8). C = alpha*(A@Bt^T)
// + beta*resid. Writes any of: Cf (fp32), Ch (bf16), CTh (bf16 transposed).
// All matrices 256x256 row-major, batch stride 65536.
// ---------------------------------------------------------------------------
__global__ __launch_bounds__(256) void ns_gemm(
    const u16* __restrict__ A, const u16* __restrict__ Bt,
    const float* __restrict__ resid, float alpha, float beta,
    float* __restrict__ Cf, u16* __restrict__ Ch, u16* __restrict__ CTh)
{
    __shared__ u16 As[128*32];
    __shared__ u16 Bs[128*32];

    size_t bb = (size_t)blockIdx.z * 65536;
    A  += bb; Bt += bb;

    int tid = threadIdx.x;
    int w = tid >> 6, lane = tid & 63;
    int wm = (w >> 1) * 64, wn = (w & 1) * 64;
    int m0 = blockIdx.y * 128, n0 = blockIdx.x * 128;

    int l4 = lane >> 2;
    int lk = (lane & 3) * 8;
    int r0 = w * 32 + l4;
    const u16* ag0 = A  + (size_t)(m0 + r0) * 256 + lk;
    const u16* ag1 = A  + (size_t)(m0 + r0 + 16) * 256 + lk;
    const u16* bg0 = Bt + (size_t)(n0 + r0) * 256 + lk;
    const u16* bg1 = Bt + (size_t)(n0 + r0 + 16) * 256 + lk;
    u16* al0 = &As[(w*32)      * 32];
    u16* al1 = &As[(w*32 + 16) * 32];
    u16* bl0 = &Bs[(w*32)      * 32];
    u16* bl1 = &Bs[(w*32 + 16) * 32];

    floatx4 acc[4][4];
    #pragma unroll
    for (int i = 0; i < 4; i++)
        #pragma unroll
        for (int j = 0; j < 4; j++)
            acc[i][j] = (floatx4){0.f, 0.f, 0.f, 0.f};

    int arow = wm + (lane & 15);
    int nrow = wn + (lane & 15);
    int koff = (lane >> 4) * 8;

    for (int k0 = 0; k0 < 256; k0 += 32) {
        gld16(ag0 + k0, al0);
        gld16(ag1 + k0, al1);
        gld16(bg0 + k0, bl0);
        gld16(bg1 + k0, bl1);
        __syncthreads();
        short8 af[4], bf[4];
        #pragma unroll
        for (int i = 0; i < 4; i++) af[i] = *(const short8*)&As[(arow + i*16)*32 + koff];
        #pragma unroll
        for (int j = 0; j < 4; j++) bf[j] = *(const short8*)&Bs[(nrow + j*16)*32 + koff];
        #pragma unroll
        for (int i = 0; i < 4; i++)
            #pragma unroll
            for (int j = 0; j < 4; j++)
                acc[i][j] = __builtin_amdgcn_mfma_f32_16x16x32_bf16(af[i], bf[j], acc[i][j], 0, 0, 0);
        __syncthreads();
    }

    int rbase = m0 + wm + (lane >> 4) * 4;
    int cbase = n0 + wn + (lane & 15);
    #pragma unroll
    for (int i = 0; i < 4; i++) {
        #pragma unroll
        for (int j = 0; j < 4; j++) {
            int col = cbase + j * 16;
            #pragma unroll
            for (int r = 0; r < 4; r++) {
                int row = rbase + i * 16 + r;
                float v = alpha * acc[i][j][r];
                if (resid) v += beta * resid[bb + (size_t)row * 256 + col];
                if (Cf)  Cf [bb + (size_t)row * 256 + col] = v;
                if (Ch)  Ch [bb + (size_t)row * 256 + col] = f2b(v);
                if (CTh) CTh[bb + (size_t)col * 256 + row] = f2b(v);
            }
        }
    }
}

// ---------------------------------------------------------------------------
// fp32 tiled GEMM (final NS polish iteration + tiny gemms).
// ---------------------------------------------------------------------------
__global__ __launch_bounds__(256) void gemm_big(
    const float* __restrict__ A, int lda, long sA,
    const float* __restrict__ B, int ldb, long sB,
    float* __restrict__ C, int ldc, long sC,
    int M, int N, int K,
    float alpha, float diagc,
    const float* __restrict__ bias,
    const float* __restrict__ resid, int ldr, long sR, float rescoef,
    int btrans)
{
    __shared__ float As[16][68];
    __shared__ float Bs[16][64];

    int bz = blockIdx.z;
    A += (size_t)bz * sA;
    B += (size_t)bz * sB;
    C += (size_t)bz * sC;

    int tid = threadIdx.x;
    int tx = tid & 15, ty = tid >> 4;
    int m0 = blockIdx.y * 64, n0 = blockIdx.x * 64;

    float acc[4][4];
    #pragma unroll
    for (int i = 0; i < 4; i++)
        #pragma unroll
        for (int j = 0; j < 4; j++) acc[i][j] = 0.f;

    for (int k0 = 0; k0 < K; k0 += 16) {
        {
            int r = tid >> 2;
            int kk = (tid & 3) * 4;
            int m = m0 + r;
            float4 av = make_float4(0.f, 0.f, 0.f, 0.f);
            if (m < M) av = *(const float4*)(A + (size_t)m * lda + k0 + kk);
            As[kk + 0][r] = av.x; As[kk + 1][r] = av.y;
            As[kk + 2][r] = av.z; As[kk + 3][r] = av.w;
        }
        if (!btrans) {
            int r = tid >> 6;
            int c = tid & 63;
            #pragma unroll
            for (int i = 0; i < 4; i++) {
                int kk = r + i * 4;
                Bs[kk][c] = B[(size_t)(k0 + kk) * ldb + n0 + c];
            }
        } else {
            int c = tid >> 2;
            int kk = (tid & 3) * 4;
            float4 bv = *(const float4*)(B + (size_t)(n0 + c) * ldb + k0 + kk);
            Bs[kk + 0][c] = bv.x; Bs[kk + 1][c] = bv.y;
            Bs[kk + 2][c] = bv.z; Bs[kk + 3][c] = bv.w;
        }
        __syncthreads();
        #pragma unroll
        for (int k = 0; k < 16; k++) {
            float4 a4 = *(const float4*)&As[k][ty * 4];
            float4 b4 = *(const float4*)&Bs[k][tx * 4];
            float a[4] = {a4.x, a4.y, a4.z, a4.w};
            float b[4] = {b4.x, b4.y, b4.z, b4.w};
            #pragma unroll
            for (int i = 0; i < 4; i++)
                #pragma unroll
                for (int j = 0; j < 4; j++) acc[i][j] += a[i] * b[j];
        }
        __syncthreads();
    }

    #pragma unroll
    for (int i = 0; i < 4; i++) {
        int m = m0 + ty * 4 + i;
        if (m >= M) continue;
        #pragma unroll
        for (int j = 0; j < 4; j++) {
            int n = n0 + tx * 4 + j;
            float v = alpha * acc[i][j];
            if (diagc != 0.f && m == n) v += diagc;
            if (bias) v += bias[n];
            if (resid) v += rescoef * resid[(size_t)bz * sR + (size_t)m * ldr + n];
            C[(size_t)m * ldc + n] = v;
        }
    }
}

// ---------------------------------------------------------------------------
__global__ __launch_bounds__(256) void ln_kernel(
    const float* __restrict__ X, float* __restrict__ OUT, u16* __restrict__ OUTH,
    const float* __restrict__ g, const float* __restrict__ b, int nrows)
{
    int row = blockIdx.x * 4 + (threadIdx.x >> 6);
    int lane = threadIdx.x & 63;
    if (row >= nrows) return;
    const float* xr = X + (size_t)row * 512;
    float v[8]; float s = 0.f, s2 = 0.f;
    #pragma unroll
    for (int i = 0; i < 8; i++) { float t = xr[lane + i * 64]; v[i] = t; s += t; s2 += t * t; }
    for (int o = 1; o < 64; o <<= 1) { s += __shfl_xor(s, o, 64); s2 += __shfl_xor(s2, o, 64); }
    float mu = s * (1.f / 512.f);
    float var = s2 * (1.f / 512.f) - mu * mu;
    float rs = rsqrtf(var + 1e-5f);
    float* orow = OUT + (size_t)row * 512;
    u16* hrow = OUTH + (size_t)row * 512;
    #pragma unroll
    for (int i = 0; i < 8; i++) {
        int j = lane + i * 64;
        float y = (v[i] - mu) * rs * g[j] + b[j];
        orow[j] = y;
        hrow[j] = f2b(y);
    }
}

// Landmark means from bf16 QKVh; writes fp32 and bf16 copies
__global__ __launch_bounds__(64) void landmarks_kernel(
    const u16* __restrict__ QKVh, float* __restrict__ QL, float* __restrict__ KL,
    u16* __restrict__ QLh, u16* __restrict__ KLh)
{
    int mm = blockIdx.x, hh = blockIdx.y;
    int d = threadIdx.x;
    const u16* base = QKVh + (size_t)(mm * 40) * 1536 + hh * 64 + d;
    float sq = 0.f, sk = 0.f;
    for (int li = 0; li < 40; li++) {
        sq += b2f(base[(size_t)li * 1536]);
        sk += b2f(base[(size_t)li * 1536 + 512]);
    }
    size_t o = ((size_t)hh * 256 + mm) * 64 + d;
    float q = sq * (1.f / 40.f), k = sk * (1.f / 40.f);
    QL[o] = q; KL[o] = k;
    QLh[o] = f2b(q); KLh[o] = f2b(k);
}

// a2 softmax: wave per row (256 cols), normalize fp32 in place + bf16 copy
__global__ __launch_bounds__(256) void softmax_a2(
    float* __restrict__ A2, u16* __restrict__ A2h, int nrows)
{
    int row = blockIdx.x * 4 + (threadIdx.x >> 6);
    int lane = threadIdx.x & 63;
    if (row >= nrows) return;
    float* p = A2 + (size_t)row * 256 + lane * 4;
    float4 v = *(float4*)p;
    float mx = fmaxf(fmaxf(v.x, v.y), fmaxf(v.z, v.w));
    for (int o = 1; o < 64; o <<= 1) mx = fmaxf(mx, __shfl_xor(mx, o, 64));
    float4 e = make_float4(__expf(v.x - mx), __expf(v.y - mx),
                           __expf(v.z - mx), __expf(v.w - mx));
    float s = e.x + e.y + e.z + e.w;
    for (int o = 1; o < 64; o <<= 1) s += __shfl_xor(s, o, 64);
    float inv = 1.f / s;
    e.x *= inv; e.y *= inv; e.z *= inv; e.w *= inv;
    *(float4*)p = e;
    u16* q = A2h + (size_t)row * 256 + lane * 4;
    q[0] = f2b(e.x); q[1] = f2b(e.y); q[2] = f2b(e.z); q[3] = f2b(e.w);
}

// wave-per-row softmax (256 cols) -> bf16 probs
__global__ __launch_bounds__(256) void softmax256_bf16(
    const float* __restrict__ S, u16* __restrict__ P, int nrows)
{
    int row = blockIdx.x * 4 + (threadIdx.x >> 6);
    int lane = threadIdx.x & 63;
    if (row >= nrows) return;
    const float* p = S + (size_t)row * 256 + lane * 4;
    float4 v = *(const float4*)p;
    float mx = fmaxf(fmaxf(v.x, v.y), fmaxf(v.z, v.w));
    for (int o = 1; o < 64; o <<= 1) mx = fmaxf(mx, __shfl_xor(mx, o, 64));
    float4 e = make_float4(__expf(v.x - mx), __expf(v.y - mx),
                           __expf(v.z - mx), __expf(v.w - mx));
    float s = e.x + e.y + e.z + e.w;
    for (int o = 1; o < 64; o <<= 1) s += __shfl_xor(s, o, 64);
    float inv = 1.f / s;
    u16* q = P + (size_t)row * 256 + lane * 4;
    q[0] = f2b(e.x * inv); q[1] = f2b(e.y * inv);
    q[2] = f2b(e.z * inv); q[3] = f2b(e.w * inv);
}

// block-per-row softmax (wide rows) -> bf16 probs
__global__ __launch_bounds__(256) void row_softmax_bf16(
    const float* __restrict__ S, u16* __restrict__ P, int ncols)
{
    int row = blockIdx.x;
    const float* p = S + (size_t)row * ncols;
    u16* q = P + (size_t)row * ncols;
    int tid = threadIdx.x;
    __shared__ float sr1[4], sr2[4];
    float mx = -1e30f;
    for (int i = tid; i < ncols; i += 256) mx = fmaxf(mx, p[i]);
    for (int o = 1; o < 64; o <<= 1) mx = fmaxf(mx, __shfl_xor(mx, o, 64));
    if ((tid & 63) == 0) sr1[tid >> 6] = mx;
    __syncthreads();
    mx = fmaxf(fmaxf(sr1[0], sr1[1]), fmaxf(sr1[2], sr1[3]));
    float s = 0.f;
    for (int i = tid; i < ncols; i += 256) s += __expf(p[i] - mx);
    for (int o = 1; o < 64; o <<= 1) s += __shfl_xor(s, o, 64);
    if ((tid & 63) == 0) sr2[tid >> 6] = s;
    __syncthreads();
    s = sr2[0] + sr2[1] + sr2[2] + sr2[3];
    float inv = 1.f / s;
    for (int i = tid; i < ncols; i += 256) q[i] = f2b(__expf(p[i] - mx) * inv);
}

__global__ __launch_bounds__(256) void a2norms_kernel(
    const float* __restrict__ A2, float* __restrict__ scal)
{
    int hh = blockIdx.x, tid = threadIdx.x;
    const float* A = A2 + (size_t)hh * 65536;
    float rs = 0.f, cs = 0.f;
    for (int j = 0; j < 256; j++) {
        rs += fabsf(A[(size_t)tid * 256 + j]);
        cs += fabsf(A[(size_t)j * 256 + tid]);
    }
    __shared__ float sm[8];
    for (int o = 1; o < 64; o <<= 1) {
        rs = fmaxf(rs, __shfl_xor(rs, o, 64));
        cs = fmaxf(cs, __shfl_xor(cs, o, 64));
    }
    if ((tid & 63) == 0) { sm[tid >> 6] = rs; sm[4 + (tid >> 6)] = cs; }
    __syncthreads();
    if (tid == 0) {
        float rm = fmaxf(fmaxf(sm[0], sm[1]), fmaxf(sm[2], sm[3]));
        float cm = fmaxf(fmaxf(sm[4], sm[5]), fmaxf(sm[6], sm[7]));
        atomicMax((unsigned int*)&scal[0], __float_as_uint(rm));
        atomicMax((unsigned int*)&scal[1], __float_as_uint(cm));
    }
}

// z0 = a2^T / denom. Writes fp32 normal, bf16 normal, bf16 transposed.
__global__ __launch_bounds__(256) void z0_kernel(
    const float* __restrict__ A2, const float* __restrict__ scal,
    float* __restrict__ Zf, u16* __restrict__ Zh, u16* __restrict__ ZTh)
{
    int i = blockIdx.x, hh = blockIdx.y, j = threadIdx.x;
    float inv = 1.f / (scal[0] * scal[1]);
    float v = A2[((size_t)hh * 256 + j) * 256 + i] * inv;
    size_t oi = ((size_t)hh * 256 + i) * 256 + j;
    size_t ot = ((size_t)hh * 256 + j) * 256 + i;
    Zf[oi] = v; Zh[oi] = f2b(v); ZTh[ot] = f2b(v);
}

// Tiny fused a1@Z for layer 1 (single token)
__global__ __launch_bounds__(256) void a1z_single(
    const u16* __restrict__ QKVh, const float* __restrict__ KL,
    const float* __restrict__ ZM, float* __restrict__ OUT, int tok)
{
    int h = blockIdx.x, tid = threadIdx.x;
    __shared__ float q[64];
    __shared__ float p[256];
    __shared__ float red[4];
    if (tid < 64) q[tid] = b2f(QKVh[(size_t)tok * 1536 + h * 64 + tid]);
    __syncthreads();
    const float* kl = KL + ((size_t)h * 256 + tid) * 64;
    float s = 0.f;
    for (int d = 0; d < 64; d++) s += q[d] * kl[d];
    float mx = s;
    for (int o = 1; o < 64; o <<= 1) mx = fmaxf(mx, __shfl_xor(mx, o, 64));
    if ((tid & 63) == 0) red[tid >> 6] = mx;
    __syncthreads();
    mx = fmaxf(fmaxf(red[0], red[1]), fmaxf(red[2], red[3]));
    float e = __expf(s - mx);
    float sum = e;
    for (int o = 1; o < 64; o <<= 1) sum += __shfl_xor(sum, o, 64);
    __syncthreads();
    if ((tid & 63) == 0) red[tid >> 6] = sum;
    __syncthreads();
    sum = red[0] + red[1] + red[2] + red[3];
    p[tid] = e / sum;
    __syncthreads();
    if (tid < 64) {
        float a = 0.f;
        for (int j = 0; j < 256; j++) a += p[j] * ZM[((size_t)h * 256 + j) * 64 + tid];
        OUT[(size_t)tok * 512 + h * 64 + tid] = a;
    }
}

// Depthwise 33-tap token conv of V (bf16), added into OUT (fp32)
__global__ __launch_bounds__(256) void conv_res(
    const u16* __restrict__ QKVh, float* __restrict__ OUT,
    const float* __restrict__ resw, int t0, int ntok)
{
    int idx = blockIdx.x * 256 + threadIdx.x;
    if (idx >= ntok * 512) return;
    int tok = t0 + (idx >> 9);
    int c = idx & 511;
    int h = c >> 6;
    const u16* vbase = QKVh + 1024 + c;
    float acc = 0.f;
    #pragma unroll 1
    for (int r = 0; r < 33; r++) {
        int ts = tok - 16 + r;
        if (ts >= 0 && ts < LPAD)
            acc += resw[h * 33 + r] * b2f(vbase[(size_t)ts * 1536]);
    }
    OUT[(size_t)tok * 512 + c] += acc;
}

// V slice of QKVh -> Vt[h][d][t] (bf16)
__global__ __launch_bounds__(256) void vtrans(
    const u16* __restrict__ QKVh, u16* __restrict__ Vt)
{
    int t0 = blockIdx.x * 64, hh = blockIdx.y;
    __shared__ u16 tile[64][65];
    #pragma unroll
    for (int ii = 0; ii < 16; ii++) {
        int idx = threadIdx.x + ii * 256;
        int t = idx >> 6, d = idx & 63;
        tile[t][d] = QKVh[(size_t)(t0 + t) * 1536 + 1024 + hh * 64 + d];
    }
    __syncthreads();
    #pragma unroll
    for (int ii = 0; ii < 16; ii++) {
        int idx = threadIdx.x + ii * 256;
        int d = idx >> 6, t = idx & 63;
        Vt[((size_t)hh * 64 + d) * LPAD + t0 + t] = tile[t][d];
    }
}

// Combine PPEG weights: W49[tap][c] = w7 + w5(if in range) + w3(if in range);
// BSUM[c] = b7+b5+b3.
__global__ void ppeg_combine(
    const float* __restrict__ w7, const float* __restrict__ w5,
    const float* __restrict__ w3, const float* __restrict__ b7,
    const float* __restrict__ b5, const float* __restrict__ b3,
    float* __restrict__ W49, float* __restrict__ BSUM)
{
    int idx = blockIdx.x * 256 + threadIdx.x;
    if (idx >= 49 * 512) return;
    int tap = idx >> 9, c = idx & 511;
    int dy = tap / 7 - 3, dx = tap % 7 - 3;
    float v = w7[c * 49 + tap];
    if (dy >= -2 && dy <= 2 && dx >= -2 && dx <= 2)
        v += w5[c * 25 + (dy + 2) * 5 + (dx + 2)];
    if (dy >= -1 && dy <= 1 && dx >= -1 && dx <= 1)
        v += w3[c * 9 + (dy + 1) * 3 + (dx + 1)];
    W49[tap * 512 + c] = v;
    if (tap == 0) BSUM[c] = b7[c] + b5[c] + b3[c];
}

// Tiled PPEG: block = 16 x-positions x 256 channels, LDS row slab reused
// across the 7 dx taps. y = blockIdx.y, channel half = blockIdx.z.
__global__ __launch_bounds__(256) void ppeg_tiled(
    const float* __restrict__ S, float* __restrict__ O,
    const float* __restrict__ W49, const float* __restrict__ BSUM)
{
    __shared__ float slab[22][256];
    int tid = threadIdx.x;
    int y = blockIdx.y;
    int x0 = blockIdx.x * 16;
    int c = blockIdx.z * 256 + tid;

    float acc[16];
    #pragma unroll
    for (int i = 0; i < 16; i++) acc[i] = 0.f;

    for (int dyi = 0; dyi < 7; dyi++) {
        int yy = y + dyi - 3;
        __syncthreads();
        bool yok = (unsigned)yy < 100u;
        #pragma unroll
        for (int p = 0; p < 22; p++) {
            int xx = x0 - 3 + p;
            float v = 0.f;
            if (yok && (unsigned)xx < 100u)
                v = S[(size_t)(1 + yy * 100 + xx) * 512 + c];
            slab[p][tid] = v;
        }
        __syncthreads();
        float w[7];
        #pragma unroll
        for (int dx = 0; dx < 7; dx++) w[dx] = W49[(dyi * 7 + dx) * 512 + c];
        #pragma unroll
        for (int xi = 0; xi < 16; xi++) {
            float a = acc[xi];
            #pragma unroll
            for (int dx = 0; dx < 7; dx++) a += slab[xi + dx][tid] * w[dx];
            acc[xi] = a;
        }
    }
    #pragma unroll
    for (int xi = 0; xi < 16; xi++) {
        int x = x0 + xi;
        if (x >= 100) break;
        size_t pos = (size_t)(1 + y * 100 + x) * 512 + c;
        O[pos] = S[pos] + BSUM[c] + acc[xi];
    }
}

__global__ __launch_bounds__(64) void final_kernel(
    const float* __restrict__ S, const float* __restrict__ g, const float* __restrict__ b,
    const float* __restrict__ w, const float* __restrict__ bb, float* __restrict__ out)
{
    int lane = threadIdx.x;
    float v[8]; float s = 0.f, s2 = 0.f;
    #pragma unroll
    for (int i = 0; i < 8; i++) { float t = S[lane + i * 64]; v[i] = t; s += t; s2 += t * t; }
    for (int o = 1; o < 64; o <<= 1) { s += __shfl_xor(s, o, 64); s2 += __shfl_xor(s2, o, 64); }
    float mu = s * (1.f / 512.f);
    float var = s2 * (1.f / 512.f) - mu * mu;
    float rs = rsqrtf(var + 1e-5f);
    float o0 = 0.f, o1 = 0.f;
    #pragma unroll
    for (int i = 0; i < 8; i++) {
        int j = lane + i * 64;
        float xn = (v[i] - mu) * rs * g[j] + b[j];
        o0 += xn * w[j * 2 + 0];
        o1 += xn * w[j * 2 + 1];
    }
    for (int o = 1; o < 64; o <<= 1) { o0 += __shfl_xor(o0, o, 64); o1 += __shfl_xor(o1, o, 64); }
    if (lane == 0) { out[0] = o0 + bb[0]; out[1] = o1 + bb[1]; }
}

__global__ void zerok(float* p, int n)
{
    int i = blockIdx.x * 256 + threadIdx.x;
    if (i < n) p[i] = 0.f;
}
__global__ void zero2k(float* p) { p[0] = 0.f; p[1] = 0.f; }
__global__ void copy512(float* dst, const float* src)
{
    int i = blockIdx.x * 256 + threadIdx.x;
    if (i < 512) dst[i] = src[i];
}
__global__ void cast_bf16(const float* __restrict__ src, u16* __restrict__ dst, int n)
{
    int i = (blockIdx.x * 256 + threadIdx.x) * 4;
    if (i >= n) return;
    float4 v = *(const float4*)(src + i);
    dst[i + 0] = f2b(v.x); dst[i + 1] = f2b(v.y);
    dst[i + 2] = f2b(v.z); dst[i + 3] = f2b(v.w);
}
// dst[b][c][r] = src[b][r][c]  (cast-transpose fp32 RxC -> bf16 CxR)
__global__ void castT(const float* __restrict__ src, u16* __restrict__ dst,
                      int R, int C, int nb)
{
    size_t idx = (size_t)blockIdx.x * 256 + threadIdx.x;
    size_t tot = (size_t)R * C * nb;
    if (idx >= tot) return;
    int rc = R * C;
    int b = (int)(idx / rc);
    int rem = (int)(idx - (size_t)b * rc);
    int c = rem / R, r = rem - c * R;
    dst[idx] = f2b(src[(size_t)b * rc + (size_t)r * C + c]);
}

// ---------------------------------------------------------------------------
extern "C" void kernel_launch(void* const* d_in, const int* in_sizes, int n_in,
                              void* d_out, int out_size, void* d_ws, size_t ws_size,
                              hipStream_t stream)
{
    const float* h     = (const float*)d_in[0];
    const float* fc1_w = (const float*)d_in[1];
    const float* fc1_b = (const float*)d_in[2];
    const float* cls   = (const float*)d_in[3];
    bool sigorder = (in_sizes[10] == 512 * 49);
    int i_l2 = sigorder ? 16 : 10;
    int i_pp = sigorder ? 10 : 16;
    const float* l_g[2]   = { (const float*)d_in[4], (const float*)d_in[i_l2 + 0] };
    const float* l_b[2]   = { (const float*)d_in[5], (const float*)d_in[i_l2 + 1] };
    const float* l_qkv[2] = { (const float*)d_in[6], (const float*)d_in[i_l2 + 2] };
    const float* l_ow[2]  = { (const float*)d_in[7], (const float*)d_in[i_l2 + 3] };
    const float* l_ob[2]  = { (const float*)d_in[8], (const float*)d_in[i_l2 + 4] };
    const float* l_rw[2]  = { (const float*)d_in[9], (const float*)d_in[i_l2 + 5] };
    const float* w7 = (const float*)d_in[i_pp + 0];
    const float* b7 = (const float*)d_in[i_pp + 1];
    const float* w5 = (const float*)d_in[i_pp + 2];
    const float* b5 = (const float*)d_in[i_pp + 3];
    const float* w3 = (const float*)d_in[i_pp + 4];
    const float* b3 = (const float*)d_in[i_pp + 5];
    const float* ng   = (const float*)d_in[22];
    const float* nbv  = (const float*)d_in[23];
    const float* fc2w = (const float*)d_in[24];
    const float* fc2b = (const float*)d_in[25];
    float* out = (float*)d_out;

    char* Wb = (char*)d_ws;
    size_t off = 0;
    auto allocB = [&](size_t bytes) { void* p = Wb + off; off = (off + bytes + 255) & ~(size_t)255; return p; };

    float* SEQ   = (float*)allocB((size_t)NSEQ * 512 * 4);
    float* XP    = (float*)allocB((size_t)LPAD * 512 * 4);
    u16*   XPh   = (u16*)  allocB((size_t)LPAD * 512 * 2);
    u16*   QKVh  = (u16*)  allocB((size_t)LPAD * 1536 * 2);
    float* QLKL  = (float*)allocB((size_t)262144 * 4);
    float* QL = QLKL, *KL = QLKL + 131072;
    u16*   QLKLh = (u16*)  allocB((size_t)262144 * 2);
    u16*   QLh = QLKLh, *KLh = QLKLh + 131072;
    float* A2   = (float*)allocB(524288 * 4);
    u16*   A2h  = (u16*)  allocB(524288 * 2);
    float* Zf0  = (float*)allocB(524288 * 4);
    float* Zf1  = (float*)allocB(524288 * 4);
    u16*   Zh0  = (u16*)  allocB(524288 * 2);
    u16*   Zh1  = (u16*)  allocB(524288 * 2);
    u16*   ZT0  = (u16*)  allocB(524288 * 2);
    u16*   ZT1  = (u16*)  allocB(524288 * 2);
    float* XZf  = (float*)allocB(524288 * 4);
    u16*   xzh  = (u16*)  allocB(524288 * 2);
    u16*   xzTh = (u16*)  allocB(524288 * 2);
    u16*   w2Th = (u16*)  allocB(524288 * 2);
    u16*   w3Th = (u16*)  allocB(524288 * 2);
    float* W2b  = (float*)allocB(524288 * 4);
    float* W3b  = (float*)allocB(524288 * 4);
    float* A3V  = (float*)allocB(131072 * 4);
    float* ZMATf= (float*)allocB(131072 * 4);
    u16*   ZMATt= (u16*)  allocB(131072 * 2);
    u16*   Vt   = (u16*)  allocB((size_t)8 * 64 * LPAD * 2);
    u16*   fc1wt= (u16*)  allocB(524288 * 2);
    u16*   qkvwt= (u16*)  allocB(786432 * 2);
    u16*   outwt= (u16*)  allocB(262144 * 2);
    float* W49  = (float*)allocB(49 * 512 * 4);
    float* BSUM = (float*)allocB(512 * 4);
    float* SCAL = (float*)allocB(16);
    void*  U1   = allocB((size_t)LPAD * 512 * 4);
    u16*   hbf  = (u16*)U1;
    float* OUT  = (float*)U1;
    float* SEQ2 = OUT;
    size_t fixed = off;

    size_t scB_b = (size_t)8 * 256 * LPAD * 4;
    size_t phB_b = (size_t)8 * 256 * LPAD * 2;
    bool batched = ws_size >= fixed + scB_b + phB_b;
    float* SC; u16* Ph;
    if (batched) {
        SC = (float*)(Wb + fixed);
        Ph = (u16*)(Wb + fixed + scB_b);
    } else {
        SC = (float*)(Wb + fixed);
        Ph = (u16*)(Wb + fixed + (size_t)256 * LPAD * 4);
    }
    u16* OUTh = (u16*)SC;

    auto mgemm = [&](const u16* A, int lda, long sA, const u16* Bt, int ldb, long sB,
                     void* C, int ldc, long sC, int M, int N, int K,
                     const float* bias, const float* resid, int ldr,
                     int relu, int qscale, int obf16, int nbatch, int ksplit, int atomic) {
        dim3 grid((N + 127) / 128, (M + 127) / 128, nbatch * ksplit);
        gemm_mfma<<<grid, 256, 0, stream>>>(A, lda, sA, Bt, ldb, sB, C, ldc, sC,
            M, N, K, ksplit, bias, resid, ldr, relu, qscale, obf16, atomic);
    };
    auto fgemm = [&](const float* A, int lda, long sA, const float* B, int ldb, long sB,
                     float* C, int ldc, long sC, int M, int N, int K,
                     float alpha, float diagc, const float* bias,
                     const float* resid, int ldr, long sR, float rescoef,
                     int btrans, int nbatch) {
        dim3 grid(N / 64, (M + 63) / 64, nbatch);
        gemm_big<<<grid, 256, 0, stream>>>(A, lda, sA, B, ldb, sB, C, ldc, sC, M, N, K,
            alpha, diagc, bias, resid, ldr, sR, rescoef, btrans);
    };

    // ---- prologue
    cast_bf16<<<(NPIX * 1024 / 4 + 255) / 256, 256, 0, stream>>>(h, hbf, NPIX * 1024);
    castT<<<(524288 + 255) / 256, 256, 0, stream>>>(fc1_w, fc1wt, 1024, 512, 1);
    mgemm(hbf, 1024, 0, fc1wt, 1024, 0, SEQ + 512, 512, 0, NPIX, 512, 1024,
          fc1_b, nullptr, 0, 1, 0, 0, 1, 1, 0);
    copy512<<<2, 256, 0, stream>>>(SEQ, cls);
    zerok<<<(PADT * 512 + 255) / 256, 256, 0, stream>>>(XP, PADT * 512);
    zerok<<<(PADT * 256 + 255) / 256, 256, 0, stream>>>((float*)XPh, PADT * 256);
    ppeg_combine<<<(49 * 512 + 255) / 256, 256, 0, stream>>>(w7, w5, w3, b7, b5, b3, W49, BSUM);

    for (int layer = 0; layer < 2; layer++) {
        const float* curSEQ = (layer == 0) ? SEQ : SEQ2;
        ln_kernel<<<(NSEQ + 3) / 4, 256, 0, stream>>>(curSEQ, XP + (size_t)PADT * 512,
            XPh + (size_t)PADT * 512, l_g[layer], l_b[layer], NSEQ);
        castT<<<(786432 + 255) / 256, 256, 0, stream>>>(l_qkv[layer], qkvwt, 512, 1536, 1);
        mgemm(XPh, 512, 0, qkvwt, 512, 0, QKVh, 1536, 0, LPAD, 1536, 512,
              nullptr, nullptr, 0, 0, 1, 1, 1, 1, 0);
        landmarks_kernel<<<dim3(256, 8), 64, 0, stream>>>(QKVh, QL, KL, QLh, KLh);
        // a2 = softmax(ql @ kl^T)  (fp32)
        fgemm(QL, 64, 16384, KL, 64, 16384, A2, 256, 65536, 256, 256, 64,
              1.f, 0.f, nullptr, nullptr, 0, 0, 0.f, 1, 8);
        softmax_a2<<<512, 256, 0, stream>>>(A2, A2h, 2048);
        zero2k<<<1, 1, 0, stream>>>(SCAL);
        a2norms_kernel<<<8, 256, 0, stream>>>(A2, SCAL);
        z0_kernel<<<dim3(256, 8), 256, 0, stream>>>(A2, SCAL, Zf0, Zh0, ZT0);

        // Newton-Schulz: 5 bf16 MFMA iterations + 1 fp32 polish iteration
        float* zcf = Zf0; u16* zch = Zh0; u16* zcTh = ZT0;
        float* znf = Zf1; u16* znh = Zh1; u16* znTh = ZT1;
        for (int it = 0; it < 5; it++) {
            ns_gemm<<<dim3(2, 2, 8), 256, 0, stream>>>(A2h, zcTh, nullptr, 1.f, 0.f,
                                                       XZf, xzh, xzTh);
            ns_gemm<<<dim3(2, 2, 8), 256, 0, stream>>>(xzh, xzTh, XZf, -1.f, 7.f,
                                                       nullptr, nullptr, w2Th);
            ns_gemm<<<dim3(2, 2, 8), 256, 0, stream>>>(xzh, w2Th, XZf, -1.f, 15.f,
                                                       nullptr, nullptr, w3Th);
            ns_gemm<<<dim3(2, 2, 8), 256, 0, stream>>>(zch, w3Th, zcf, -0.25f, 3.25f,
                                                       znf, znh, znTh);
            float* tf = zcf; zcf = znf; znf = tf;
            u16* th = zch; zch = znh; znh = th;
            u16* tt = zcTh; zcTh = znTh; znTh = tt;
        }
        // fp32 polish: zn = 0.25 zc (13I - XZ(15I - XZ(7I - XZ)))
        fgemm(A2, 256, 65536, zcf, 256, 65536, XZf, 256, 65536, 256, 256, 256,
              1.f, 0.f, nullptr, nullptr, 0, 0, 0.f, 0, 8);
        fgemm(XZf, 256, 65536, XZf, 256, 65536, W2b, 256, 65536, 256, 256, 256,
              1.f, 15.f, nullptr, XZf, 256, 65536, -7.f, 0, 8);
        fgemm(XZf, 256, 65536, W2b, 256, 65536, W3b, 256, 65536, 256, 256, 256,
              -1.f, 13.f, nullptr, nullptr, 0, 0, 0.f, 0, 8);
        fgemm(zcf, 256, 65536, W3b, 256, 65536, znf, 256, 65536, 256, 256, 256,
              0.25f, 0.f, nullptr, nullptr, 0, 0, 0.f, 0, 8);
        float* zfin = znf;

        // a3v = softmax(ql @ k^T) @ v  via MFMA
        vtrans<<<dim3(160, 8), 256, 0, stream>>>(QKVh, Vt);
        zerok<<<512, 256, 0, stream>>>(A3V, 131072);
        if (batched) {
            mgemm(QLh, 64, 16384, QKVh + 512, 1536, 64, SC, LPAD, (long)256 * LPAD,
                  256, LPAD, 64, nullptr, nullptr, 0, 0, 0, 0, 8, 1, 0);
            row_softmax_bf16<<<2048, 256, 0, stream>>>(SC, Ph, LPAD);
            mgemm(Ph, LPAD, (long)256 * LPAD, Vt, LPAD, (long)64 * LPAD, A3V, 64, 16384,
                  256, 64, LPAD, nullptr, nullptr, 0, 0, 0, 0, 8, 40, 1);
        } else {
            for (int hh = 0; hh < 8; hh++) {
                mgemm(QLh + (size_t)hh * 16384, 64, 0, QKVh + 512 + hh * 64, 1536, 0,
                      SC, LPAD, 0, 256, LPAD, 64, nullptr, nullptr, 0, 0, 0, 0, 1, 1, 0);
                row_softmax_bf16<<<256, 256, 0, stream>>>(SC, Ph, LPAD);
                mgemm(Ph, LPAD, 0, Vt + (size_t)hh * 64 * LPAD, LPAD, 0,
                      A3V + (size_t)hh * 16384, 64, 0, 256, 64, LPAD,
                      nullptr, nullptr, 0, 0, 0, 0, 1, 40, 1);
            }
        }
        // ZMAT = pinv(a2) @ a3v  (fp32)
        fgemm(zfin, 256, 65536, A3V, 64, 16384, ZMATf, 64, 16384, 256, 64, 256,
              1.f, 0.f, nullptr, nullptr, 0, 0, 0.f, 0, 8);

        if (layer == 0) {
            castT<<<(131072 + 255) / 256, 256, 0, stream>>>(ZMATf, ZMATt, 256, 64, 8);
            if (batched) {
                mgemm(QKVh, 1536, 64, KLh, 64, 16384, SC, 256, (long)LPAD * 256,
                      LPAD, 256, 64, nullptr, nullptr, 0, 0, 0, 0, 8, 1, 0);
                softmax256_bf16<<<8 * LPAD / 4, 256, 0, stream>>>(SC, Ph, 8 * LPAD);
                mgemm(Ph, 256, (long)LPAD * 256, ZMATt, 256, 16384, OUT, 512, 64,
                      LPAD, 64, 256, nullptr, nullptr, 0, 0, 0, 0, 8, 1, 0);
            } else {
                for (int hh = 0; hh < 8; hh++) {
                    mgemm(QKVh + hh * 64, 1536, 0, KLh + (size_t)hh * 16384, 64, 0,
                          SC, 256, 0, LPAD, 256, 64, nullptr, nullptr, 0, 0, 0, 0, 1, 1, 0);
                    softmax256_bf16<<<LPAD / 4, 256, 0, stream>>>(SC, Ph, LPAD);
                    mgemm(Ph, 256, 0, ZMATt + (size_t)hh * 16384, 256, 0,
                          OUT + hh * 64, 512, 0, LPAD, 64, 256,
                          nullptr, nullptr, 0, 0, 0, 0, 1, 1, 0);
                }
            }
            conv_res<<<(NSEQ * 512 + 255) / 256, 256, 0, stream>>>(QKVh, OUT, l_rw[0], PADT, NSEQ);
            cast_bf16<<<(NSEQ * 512 / 4 + 255) / 256, 256, 0, stream>>>(
                OUT + (size_t)PADT * 512, OUTh, NSEQ * 512);
            castT<<<(262144 + 255) / 256, 256, 0, stream>>>(l_ow[0], outwt, 512, 512, 1);
            mgemm(OUTh, 512, 0, outwt, 512, 0, SEQ, 512, 0, NSEQ, 512, 512,
                  l_ob[0], XP + (size_t)PADT * 512, 512, 0, 0, 0, 1, 1, 0);
            // PPEG
            ppeg_tiled<<<dim3(7, 100, 2), 256, 0, stream>>>(SEQ, SEQ2, W49, BSUM);
            copy512<<<2, 256, 0, stream>>>(SEQ2, SEQ);
        } else {
            a1z_single<<<8, 256, 0, stream>>>(QKVh, KL, ZMATf, OUT, PADT);
            conv_res<<<2, 256, 0, stream>>>(QKVh, OUT, l_rw[1], PADT, 1);
            fgemm(OUT + (size_t)PADT * 512, 512, 0, l_ow[1], 512, 0, SEQ, 512, 0,
                  1, 512, 512, 1.f, 0.f, l_ob[1],
                  XP + (size_t)PADT * 512, 512, 0, 1.f, 0, 1);
        }
    }
    final_kernel<<<1, 64, 0, stream>>>(SEQ, ng, nbv, fc2w, fc2b, out);
    (void)n_in; (void)out_size;
}

// Round 6
// 3068.920 us; speedup vs baseline: 1.1050x; 1.1050x over previous
//
#include <hip/hip_runtime.h>
#include <math.h>

#define LPAD  10240
#define NSEQ  10001
#define PADT  239
#define NPIX  10000

typedef unsigned short u16;
typedef __attribute__((ext_vector_type(8))) short short8;
typedef __attribute__((ext_vector_type(4))) float floatx4;

__device__ __forceinline__ float b2f(u16 u){ return __uint_as_float(((unsigned)u)<<16); }
__device__ __forceinline__ u16 f2b(float f){
    unsigned x = __float_as_uint(f);
    return (u16)((x + 0x7FFFu + ((x>>16)&1u)) >> 16);
}
__device__ __forceinline__ void gld16(const void* g, void* l){
    __builtin_amdgcn_global_load_lds(
        (const __attribute__((address_space(1))) unsigned int*)g,
        (__attribute__((address_space(3))) unsigned int*)l, 16, 0, 0);
}

// ---------------------------------------------------------------------------
// bf16 MFMA GEMM: C = A @ Bt^T (+bias)(+resid)(relu)(qscale). A: M x K bf16
// row-major (lda, batch sA). Bt: N x K bf16 (ldb, sB). C fp32 or bf16 (obf16),
// 128x128 tile, 4 waves, 16x16x32 MFMA, global_load_lds width-16 staging.
// ---------------------------------------------------------------------------
__global__ __launch_bounds__(256) void gemm_mfma(
    const u16* __restrict__ A, int lda, long sA,
    const u16* __restrict__ Bt, int ldb, long sB,
    void* __restrict__ Cv, int ldc, long sC,
    int M, int N, int K, int ksplit,
    const float* __restrict__ bias,
    const float* __restrict__ resid, int ldr,
    int relu, int qscale, int obf16, int atomic)
{
    __shared__ u16 As[128*32];
    __shared__ u16 Bs[128*32];

    int bz = blockIdx.z / ksplit;
    int ks = blockIdx.z - bz * ksplit;
    A  += (size_t)bz * sA;
    Bt += (size_t)bz * sB;

    int kchunk = (K + ksplit - 1) / ksplit;
    kchunk = (kchunk + 31) & ~31;
    int kbeg = ks * kchunk;
    int kend = kbeg + kchunk; if (kend > K) kend = K;

    int tid = threadIdx.x;
    int w = tid >> 6, lane = tid & 63;
    int wm = (w >> 1) * 64, wn = (w & 1) * 64;
    int m0 = blockIdx.y * 128, n0 = blockIdx.x * 128;

    int l4 = lane >> 2;
    int lk = (lane & 3) * 8;
    int r0 = w * 32 + l4;
    int am0 = m0 + r0;      if (am0 > M-1) am0 = M-1;
    int am1 = m0 + r0 + 16; if (am1 > M-1) am1 = M-1;
    int bn0 = n0 + r0;      if (bn0 > N-1) bn0 = N-1;
    int bn1 = n0 + r0 + 16; if (bn1 > N-1) bn1 = N-1;
    const u16* ag0 = A  + (size_t)am0 * lda + lk;
    const u16* ag1 = A  + (size_t)am1 * lda + lk;
    const u16* bg0 = Bt + (size_t)bn0 * ldb + lk;
    const u16* bg1 = Bt + (size_t)bn1 * ldb + lk;
    u16* sa0 = &As[(w*32)      * 32];
    u16* sa1 = &As[(w*32 + 16) * 32];
    u16* sb0 = &Bs[(w*32)      * 32];
    u16* sb1 = &Bs[(w*32 + 16) * 32];

    floatx4 acc[4][4];
    #pragma unroll
    for (int i = 0; i < 4; i++)
        #pragma unroll
        for (int j = 0; j < 4; j++)
            acc[i][j] = (floatx4){0.f, 0.f, 0.f, 0.f};

    int arow = wm + (lane & 15);
    int nrow = wn + (lane & 15);
    int koff = (lane >> 4) * 8;

    for (int k0 = kbeg; k0 < kend; k0 += 32) {
        gld16(ag0 + k0, sa0);
        gld16(ag1 + k0, sa1);
        gld16(bg0 + k0, sb0);
        gld16(bg1 + k0, sb1);
        __syncthreads();
        short8 af[4], bf[4];
        #pragma unroll
        for (int i = 0; i < 4; i++) af[i] = *(const short8*)&As[(arow + i*16)*32 + koff];
        #pragma unroll
        for (int j = 0; j < 4; j++) bf[j] = *(const short8*)&Bs[(nrow + j*16)*32 + koff];
        #pragma unroll
        for (int i = 0; i < 4; i++)
            #pragma unroll
            for (int j = 0; j < 4; j++)
                acc[i][j] = __builtin_amdgcn_mfma_f32_16x16x32_bf16(af[i], bf[j], acc[i][j], 0, 0, 0);
        __syncthreads();
    }

    float* Cf = (float*)Cv;
    u16*   Ch = (u16*)Cv;
    size_t cb = (size_t)bz * sC;
    int rbase = m0 + wm + (lane >> 4) * 4;
    int cbase = n0 + wn + (lane & 15);
    #pragma unroll
    for (int i = 0; i < 4; i++) {
        #pragma unroll
        for (int j = 0; j < 4; j++) {
            int col = cbase + j * 16;
            if (col >= N) continue;
            float bcol = bias ? bias[col] : 0.f;
            #pragma unroll
            for (int r = 0; r < 4; r++) {
                int row = rbase + i * 16 + r;
                if (row >= M) continue;
                float v = acc[i][j][r];
                if (qscale && col < 512) v *= 0.125f;
                v += bcol;
                if (resid) v += resid[(size_t)row * ldr + col];
                if (relu) v = fmaxf(v, 0.f);
                size_t ci = cb + (size_t)row * ldc + col;
                if (obf16) Ch[ci] = f2b(v);
                else if (atomic) atomicAdd(&Cf[ci], v);
                else Cf[ci] = v;
            }
        }
    }
}

// ---------------------------------------------------------------------------
// Newton-Schulz paired MFMA gemm, 256x256x256 per head, batch 8.
// grid (2,2,8) for single set, (2,2,16) to run two independent gemms.
// C = alpha*(A@Bt^T) + beta*resid. Outputs Cf (fp32) and/or Ch (bf16),
// both row-major coalesced — NO transposed scatter (round-4's bug);
// transposed products are obtained as (XY)^T = Y^T X^T with swapped operands.
// ---------------------------------------------------------------------------
__global__ __launch_bounds__(256) void ns_gemm(
    const u16* __restrict__ A0, const u16* __restrict__ B0,
    const float* __restrict__ r0, float al0, float be0,
    float* __restrict__ Cf0, u16* __restrict__ Ch0,
    const u16* __restrict__ A1, const u16* __restrict__ B1,
    const float* __restrict__ r1, float al1, float be1,
    float* __restrict__ Cf1, u16* __restrict__ Ch1)
{
    __shared__ u16 As[128*32];
    __shared__ u16 Bs[128*32];

    int zz = blockIdx.z;
    int hh = zz & 7;
    bool p = zz >= 8;
    const u16* A  = p ? A1 : A0;
    const u16* Bt = p ? B1 : B0;
    const float* resid = p ? r1 : r0;
    float alpha = p ? al1 : al0;
    float beta  = p ? be1 : be0;
    float* Cf = p ? Cf1 : Cf0;
    u16*   Ch = p ? Ch1 : Ch0;

    size_t bb = (size_t)hh * 65536;
    A  += bb; Bt += bb;

    int tid = threadIdx.x;
    int w = tid >> 6, lane = tid & 63;
    int wm = (w >> 1) * 64, wn = (w & 1) * 64;
    int m0 = blockIdx.y * 128, n0 = blockIdx.x * 128;

    int l4 = lane >> 2;
    int lk = (lane & 3) * 8;
    int r0i = w * 32 + l4;
    const u16* ag0 = A  + (size_t)(m0 + r0i) * 256 + lk;
    const u16* ag1 = A  + (size_t)(m0 + r0i + 16) * 256 + lk;
    const u16* bg0 = Bt + (size_t)(n0 + r0i) * 256 + lk;
    const u16* bg1 = Bt + (size_t)(n0 + r0i + 16) * 256 + lk;
    u16* sa0 = &As[(w*32)      * 32];
    u16* sa1 = &As[(w*32 + 16) * 32];
    u16* sb0 = &Bs[(w*32)      * 32];
    u16* sb1 = &Bs[(w*32 + 16) * 32];

    floatx4 acc[4][4];
    #pragma unroll
    for (int i = 0; i < 4; i++)
        #pragma unroll
        for (int j = 0; j < 4; j++)
            acc[i][j] = (floatx4){0.f, 0.f, 0.f, 0.f};

    int arow = wm + (lane & 15);
    int nrow = wn + (lane & 15);
    int koff = (lane >> 4) * 8;

    for (int k0 = 0; k0 < 256; k0 += 32) {
        gld16(ag0 + k0, sa0);
        gld16(ag1 + k0, sa1);
        gld16(bg0 + k0, sb0);
        gld16(bg1 + k0, sb1);
        __syncthreads();
        short8 af[4], bf[4];
        #pragma unroll
        for (int i = 0; i < 4; i++) af[i] = *(const short8*)&As[(arow + i*16)*32 + koff];
        #pragma unroll
        for (int j = 0; j < 4; j++) bf[j] = *(const short8*)&Bs[(nrow + j*16)*32 + koff];
        #pragma unroll
        for (int i = 0; i < 4; i++)
            #pragma unroll
            for (int j = 0; j < 4; j++)
                acc[i][j] = __builtin_amdgcn_mfma_f32_16x16x32_bf16(af[i], bf[j], acc[i][j], 0, 0, 0);
        __syncthreads();
    }

    int rbase = m0 + wm + (lane >> 4) * 4;
    int cbase = n0 + wn + (lane & 15);
    #pragma unroll
    for (int i = 0; i < 4; i++) {
        #pragma unroll
        for (int j = 0; j < 4; j++) {
            int col = cbase + j * 16;
            #pragma unroll
            for (int r = 0; r < 4; r++) {
                int row = rbase + i * 16 + r;
                float v = alpha * acc[i][j][r];
                size_t ci = bb + (size_t)row * 256 + col;
                if (resid) v += beta * resid[ci];
                if (Cf) Cf[ci] = v;
                if (Ch) Ch[ci] = f2b(v);
            }
        }
    }
}

// ---------------------------------------------------------------------------
// fp32 tiled GEMM (final NS polish iteration + tiny gemms).
// ---------------------------------------------------------------------------
__global__ __launch_bounds__(256) void gemm_big(
    const float* __restrict__ A, int lda, long sA,
    const float* __restrict__ B, int ldb, long sB,
    float* __restrict__ C, int ldc, long sC,
    int M, int N, int K,
    float alpha, float diagc,
    const float* __restrict__ bias,
    const float* __restrict__ resid, int ldr, long sR, float rescoef,
    int btrans)
{
    __shared__ float As[16][68];
    __shared__ float Bs[16][64];

    int bz = blockIdx.z;
    A += (size_t)bz * sA;
    B += (size_t)bz * sB;
    C += (size_t)bz * sC;

    int tid = threadIdx.x;
    int tx = tid & 15, ty = tid >> 4;
    int m0 = blockIdx.y * 64, n0 = blockIdx.x * 64;

    float acc[4][4];
    #pragma unroll
    for (int i = 0; i < 4; i++)
        #pragma unroll
        for (int j = 0; j < 4; j++) acc[i][j] = 0.f;

    for (int k0 = 0; k0 < K; k0 += 16) {
        {
            int r = tid >> 2;
            int kk = (tid & 3) * 4;
            int m = m0 + r;
            float4 av = make_float4(0.f, 0.f, 0.f, 0.f);
            if (m < M) av = *(const float4*)(A + (size_t)m * lda + k0 + kk);
            As[kk + 0][r] = av.x; As[kk + 1][r] = av.y;
            As[kk + 2][r] = av.z; As[kk + 3][r] = av.w;
        }
        if (!btrans) {
            int r = tid >> 6;
            int c = tid & 63;
            #pragma unroll
            for (int i = 0; i < 4; i++) {
                int kk = r + i * 4;
                Bs[kk][c] = B[(size_t)(k0 + kk) * ldb + n0 + c];
            }
        } else {
            int c = tid >> 2;
            int kk = (tid & 3) * 4;
            float4 bv = *(const float4*)(B + (size_t)(n0 + c) * ldb + k0 + kk);
            Bs[kk + 0][c] = bv.x; Bs[kk + 1][c] = bv.y;
            Bs[kk + 2][c] = bv.z; Bs[kk + 3][c] = bv.w;
        }
        __syncthreads();
        #pragma unroll
        for (int k = 0; k < 16; k++) {
            float4 a4 = *(const float4*)&As[k][ty * 4];
            float4 b4 = *(const float4*)&Bs[k][tx * 4];
            float a[4] = {a4.x, a4.y, a4.z, a4.w};
            float b[4] = {b4.x, b4.y, b4.z, b4.w};
            #pragma unroll
            for (int i = 0; i < 4; i++)
                #pragma unroll
                for (int j = 0; j < 4; j++) acc[i][j] += a[i] * b[j];
        }
        __syncthreads();
    }

    #pragma unroll
    for (int i = 0; i < 4; i++) {
        int m = m0 + ty * 4 + i;
        if (m >= M) continue;
        #pragma unroll
        for (int j = 0; j < 4; j++) {
            int n = n0 + tx * 4 + j;
            float v = alpha * acc[i][j];
            if (diagc != 0.f && m == n) v += diagc;
            if (bias) v += bias[n];
            if (resid) v += rescoef * resid[(size_t)bz * sR + (size_t)m * ldr + n];
            C[(size_t)m * ldc + n] = v;
        }
    }
}

// ---------------------------------------------------------------------------
__global__ __launch_bounds__(256) void ln_kernel(
    const float* __restrict__ X, float* __restrict__ OUT, u16* __restrict__ OUTH,
    const float* __restrict__ g, const float* __restrict__ b, int nrows)
{
    int row = blockIdx.x * 4 + (threadIdx.x >> 6);
    int lane = threadIdx.x & 63;
    if (row >= nrows) return;
    const float* xr = X + (size_t)row * 512;
    float v[8]; float s = 0.f, s2 = 0.f;
    #pragma unroll
    for (int i = 0; i < 8; i++) { float t = xr[lane + i * 64]; v[i] = t; s += t; s2 += t * t; }
    for (int o = 1; o < 64; o <<= 1) { s += __shfl_xor(s, o, 64); s2 += __shfl_xor(s2, o, 64); }
    float mu = s * (1.f / 512.f);
    float var = s2 * (1.f / 512.f) - mu * mu;
    float rs = rsqrtf(var + 1e-5f);
    float* orow = OUT + (size_t)row * 512;
    u16* hrow = OUTH + (size_t)row * 512;
    #pragma unroll
    for (int i = 0; i < 8; i++) {
        int j = lane + i * 64;
        float y = (v[i] - mu) * rs * g[j] + b[j];
        orow[j] = y;
        hrow[j] = f2b(y);
    }
}

// Landmark means from bf16 QKVh; writes fp32 and bf16 copies
__global__ __launch_bounds__(64) void landmarks_kernel(
    const u16* __restrict__ QKVh, float* __restrict__ QL, float* __restrict__ KL,
    u16* __restrict__ QLh, u16* __restrict__ KLh)
{
    int mm = blockIdx.x, hh = blockIdx.y;
    int d = threadIdx.x;
    const u16* base = QKVh + (size_t)(mm * 40) * 1536 + hh * 64 + d;
    float sq = 0.f, sk = 0.f;
    for (int li = 0; li < 40; li++) {
        sq += b2f(base[(size_t)li * 1536]);
        sk += b2f(base[(size_t)li * 1536 + 512]);
    }
    size_t o = ((size_t)hh * 256 + mm) * 64 + d;
    float q = sq * (1.f / 40.f), k = sk * (1.f / 40.f);
    QL[o] = q; KL[o] = k;
    QLh[o] = f2b(q); KLh[o] = f2b(k);
}

// a2 softmax: wave per row (256 cols), normalize fp32 in place + bf16 copy
__global__ __launch_bounds__(256) void softmax_a2(
    float* __restrict__ A2, u16* __restrict__ A2h, int nrows)
{
    int row = blockIdx.x * 4 + (threadIdx.x >> 6);
    int lane = threadIdx.x & 63;
    if (row >= nrows) return;
    float* p = A2 + (size_t)row * 256 + lane * 4;
    float4 v = *(float4*)p;
    float mx = fmaxf(fmaxf(v.x, v.y), fmaxf(v.z, v.w));
    for (int o = 1; o < 64; o <<= 1) mx = fmaxf(mx, __shfl_xor(mx, o, 64));
    float4 e = make_float4(__expf(v.x - mx), __expf(v.y - mx),
                           __expf(v.z - mx), __expf(v.w - mx));
    float s = e.x + e.y + e.z + e.w;
    for (int o = 1; o < 64; o <<= 1) s += __shfl_xor(s, o, 64);
    float inv = 1.f / s;
    e.x *= inv; e.y *= inv; e.z *= inv; e.w *= inv;
    *(float4*)p = e;
    u16* q = A2h + (size_t)row * 256 + lane * 4;
    q[0] = f2b(e.x); q[1] = f2b(e.y); q[2] = f2b(e.z); q[3] = f2b(e.w);
}

// wave-per-row softmax (256 cols) -> bf16 probs
__global__ __launch_bounds__(256) void softmax256_bf16(
    const float* __restrict__ S, u16* __restrict__ P, int nrows)
{
    int row = blockIdx.x * 4 + (threadIdx.x >> 6);
    int lane = threadIdx.x & 63;
    if (row >= nrows) return;
    const float* p = S + (size_t)row * 256 + lane * 4;
    float4 v = *(const float4*)p;
    float mx = fmaxf(fmaxf(v.x, v.y), fmaxf(v.z, v.w));
    for (int o = 1; o < 64; o <<= 1) mx = fmaxf(mx, __shfl_xor(mx, o, 64));
    float4 e = make_float4(__expf(v.x - mx), __expf(v.y - mx),
                           __expf(v.z - mx), __expf(v.w - mx));
    float s = e.x + e.y + e.z + e.w;
    for (int o = 1; o < 64; o <<= 1) s += __shfl_xor(s, o, 64);
    float inv = 1.f / s;
    u16* q = P + (size_t)row * 256 + lane * 4;
    q[0] = f2b(e.x * inv); q[1] = f2b(e.y * inv);
    q[2] = f2b(e.z * inv); q[3] = f2b(e.w * inv);
}

// block-per-row softmax (wide rows) -> bf16 probs
__global__ __launch_bounds__(256) void row_softmax_bf16(
    const float* __restrict__ S, u16* __restrict__ P, int ncols)
{
    int row = blockIdx.x;
    const float* p = S + (size_t)row * ncols;
    u16* q = P + (size_t)row * ncols;
    int tid = threadIdx.x;
    __shared__ float sr1[4], sr2[4];
    float mx = -1e30f;
    for (int i = tid; i < ncols; i += 256) mx = fmaxf(mx, p[i]);
    for (int o = 1; o < 64; o <<= 1) mx = fmaxf(mx, __shfl_xor(mx, o, 64));
    if ((tid & 63) == 0) sr1[tid >> 6] = mx;
    __syncthreads();
    mx = fmaxf(fmaxf(sr1[0], sr1[1]), fmaxf(sr1[2], sr1[3]));
    float s = 0.f;
    for (int i = tid; i < ncols; i += 256) s += __expf(p[i] - mx);
    for (int o = 1; o < 64; o <<= 1) s += __shfl_xor(s, o, 64);
    if ((tid & 63) == 0) sr2[tid >> 6] = s;
    __syncthreads();
    s = sr2[0] + sr2[1] + sr2[2] + sr2[3];
    float inv = 1.f / s;
    for (int i = tid; i < ncols; i += 256) q[i] = f2b(__expf(p[i] - mx) * inv);
}

__global__ __launch_bounds__(256) void a2norms_kernel(
    const float* __restrict__ A2, float* __restrict__ scal)
{
    int hh = blockIdx.x, tid = threadIdx.x;
    const float* A = A2 + (size_t)hh * 65536;
    float rs = 0.f, cs = 0.f;
    for (int j = 0; j < 256; j++) {
        rs += fabsf(A[(size_t)tid * 256 + j]);
        cs += fabsf(A[(size_t)j * 256 + tid]);
    }
    __shared__ float sm[8];
    for (int o = 1; o < 64; o <<= 1) {
        rs = fmaxf(rs, __shfl_xor(rs, o, 64));
        cs = fmaxf(cs, __shfl_xor(cs, o, 64));
    }
    if ((tid & 63) == 0) { sm[tid >> 6] = rs; sm[4 + (tid >> 6)] = cs; }
    __syncthreads();
    if (tid == 0) {
        float rm = fmaxf(fmaxf(sm[0], sm[1]), fmaxf(sm[2], sm[3]));
        float cm = fmaxf(fmaxf(sm[4], sm[5]), fmaxf(sm[6], sm[7]));
        atomicMax((unsigned int*)&scal[0], __float_as_uint(rm));
        atomicMax((unsigned int*)&scal[1], __float_as_uint(cm));
    }
}

// z0 = a2^T / denom. Writes fp32 + bf16, both row-major and transposed.
__global__ __launch_bounds__(256) void z0_kernel(
    const float* __restrict__ A2, const float* __restrict__ scal,
    float* __restrict__ Zf, float* __restrict__ ZTf,
    u16* __restrict__ Zh, u16* __restrict__ ZTh)
{
    int i = blockIdx.x, hh = blockIdx.y, j = threadIdx.x;
    float inv = 1.f / (scal[0] * scal[1]);
    float v = A2[((size_t)hh * 256 + j) * 256 + i] * inv;
    size_t oi = ((size_t)hh * 256 + i) * 256 + j;
    size_t ot = ((size_t)hh * 256 + j) * 256 + i;
    Zf[oi] = v; ZTf[ot] = v;
    Zh[oi] = f2b(v); ZTh[ot] = f2b(v);
}

// Tiny fused a1@Z for layer 1 (single token)
__global__ __launch_bounds__(256) void a1z_single(
    const u16* __restrict__ QKVh, const float* __restrict__ KL,
    const float* __restrict__ ZM, float* __restrict__ OUT, int tok)
{
    int h = blockIdx.x, tid = threadIdx.x;
    __shared__ float q[64];
    __shared__ float p[256];
    __shared__ float red[4];
    if (tid < 64) q[tid] = b2f(QKVh[(size_t)tok * 1536 + h * 64 + tid]);
    __syncthreads();
    const float* kl = KL + ((size_t)h * 256 + tid) * 64;
    float s = 0.f;
    for (int d = 0; d < 64; d++) s += q[d] * kl[d];
    float mx = s;
    for (int o = 1; o < 64; o <<= 1) mx = fmaxf(mx, __shfl_xor(mx, o, 64));
    if ((tid & 63) == 0) red[tid >> 6] = mx;
    __syncthreads();
    mx = fmaxf(fmaxf(red[0], red[1]), fmaxf(red[2], red[3]));
    float e = __expf(s - mx);
    float sum = e;
    for (int o = 1; o < 64; o <<= 1) sum += __shfl_xor(sum, o, 64);
    __syncthreads();
    if ((tid & 63) == 0) red[tid >> 6] = sum;
    __syncthreads();
    sum = red[0] + red[1] + red[2] + red[3];
    p[tid] = e / sum;
    __syncthreads();
    if (tid < 64) {
        float a = 0.f;
        for (int j = 0; j < 256; j++) a += p[j] * ZM[((size_t)h * 256 + j) * 64 + tid];
        OUT[(size_t)tok * 512 + h * 64 + tid] = a;
    }
}

// Depthwise 33-tap token conv of V (bf16), added into OUT (fp32)
__global__ __launch_bounds__(256) void conv_res(
    const u16* __restrict__ QKVh, float* __restrict__ OUT,
    const float* __restrict__ resw, int t0, int ntok)
{
    int idx = blockIdx.x * 256 + threadIdx.x;
    if (idx >= ntok * 512) return;
    int tok = t0 + (idx >> 9);
    int c = idx & 511;
    int h = c >> 6;
    const u16* vbase = QKVh + 1024 + c;
    float acc = 0.f;
    #pragma unroll 1
    for (int r = 0; r < 33; r++) {
        int ts = tok - 16 + r;
        if (ts >= 0 && ts < LPAD)
            acc += resw[h * 33 + r] * b2f(vbase[(size_t)ts * 1536]);
    }
    OUT[(size_t)tok * 512 + c] += acc;
}

// V slice of QKVh -> Vt[h][d][t] (bf16)
__global__ __launch_bounds__(256) void vtrans(
    const u16* __restrict__ QKVh, u16* __restrict__ Vt)
{
    int t0 = blockIdx.x * 64, hh = blockIdx.y;
    __shared__ u16 tile[64][65];
    #pragma unroll
    for (int ii = 0; ii < 16; ii++) {
        int idx = threadIdx.x + ii * 256;
        int t = idx >> 6, d = idx & 63;
        tile[t][d] = QKVh[(size_t)(t0 + t) * 1536 + 1024 + hh * 64 + d];
    }
    __syncthreads();
    #pragma unroll
    for (int ii = 0; ii < 16; ii++) {
        int idx = threadIdx.x + ii * 256;
        int d = idx >> 6, t = idx & 63;
        Vt[((size_t)hh * 64 + d) * LPAD + t0 + t] = tile[t][d];
    }
}

// Combine PPEG weights: W49[tap][c] = w7 + w5(in range) + w3(in range);
// BSUM[c] = b7+b5+b3.
__global__ void ppeg_combine(
    const float* __restrict__ w7, const float* __restrict__ w5,
    const float* __restrict__ w3, const float* __restrict__ b7,
    const float* __restrict__ b5, const float* __restrict__ b3,
    float* __restrict__ W49, float* __restrict__ BSUM)
{
    int idx = blockIdx.x * 256 + threadIdx.x;
    if (idx >= 49 * 512) return;
    int tap = idx >> 9, c = idx & 511;
    int dy = tap / 7 - 3, dx = tap % 7 - 3;
    float v = w7[c * 49 + tap];
    if (dy >= -2 && dy <= 2 && dx >= -2 && dx <= 2)
        v += w5[c * 25 + (dy + 2) * 5 + (dx + 2)];
    if (dy >= -1 && dy <= 1 && dx >= -1 && dx <= 1)
        v += w3[c * 9 + (dy + 1) * 3 + (dx + 1)];
    W49[tap * 512 + c] = v;
    if (tap == 0) BSUM[c] = b7[c] + b5[c] + b3[c];
}

// PPEG: one position per block (20000-block parallelism), combined weights,
// wave-uniform interior fast path (88% of blocks branch-free).
__global__ __launch_bounds__(256) void ppeg_fast(
    const float* __restrict__ S, float* __restrict__ O,
    const float* __restrict__ W49, const float* __restrict__ BSUM)
{
    int pos = blockIdx.x;
    int y = pos / 100, x = pos - y * 100;
    int c = blockIdx.y * 256 + threadIdx.x;
    const float* Sc = S + 512 + c;    // +512: skip cls token
    float acc = Sc[(size_t)pos * 512] + BSUM[c];
    if (y >= 3 && y < 97 && x >= 3 && x < 97) {
        for (int dy = -3; dy <= 3; dy++) {
            #pragma unroll
            for (int dx = -3; dx <= 3; dx++)
                acc += Sc[(size_t)(pos + dy * 100 + dx) * 512]
                     * W49[((dy + 3) * 7 + (dx + 3)) * 512 + c];
        }
    } else {
        for (int dy = -3; dy <= 3; dy++) {
            int yy = y + dy; if ((unsigned)yy >= 100u) continue;
            #pragma unroll
            for (int dx = -3; dx <= 3; dx++) {
                int xx = x + dx; if ((unsigned)xx >= 100u) continue;
                acc += Sc[(size_t)(yy * 100 + xx) * 512]
                     * W49[((dy + 3) * 7 + (dx + 3)) * 512 + c];
            }
        }
    }
    O[(size_t)(1 + pos) * 512 + c] = acc;
}

__global__ __launch_bounds__(64) void final_kernel(
    const float* __restrict__ S, const float* __restrict__ g, const float* __restrict__ b,
    const float* __restrict__ w, const float* __restrict__ bb, float* __restrict__ out)
{
    int lane = threadIdx.x;
    float v[8]; float s = 0.f, s2 = 0.f;
    #pragma unroll
    for (int i = 0; i < 8; i++) { float t = S[lane + i * 64]; v[i] = t; s += t; s2 += t * t; }
    for (int o = 1; o < 64; o <<= 1) { s += __shfl_xor(s, o, 64); s2 += __shfl_xor(s2, o, 64); }
    float mu = s * (1.f / 512.f);
    float var = s2 * (1.f / 512.f) - mu * mu;
    float rs = rsqrtf(var + 1e-5f);
    float o0 = 0.f, o1 = 0.f;
    #pragma unroll
    for (int i = 0; i < 8; i++) {
        int j = lane + i * 64;
        float xn = (v[i] - mu) * rs * g[j] + b[j];
        o0 += xn * w[j * 2 + 0];
        o1 += xn * w[j * 2 + 1];
    }
    for (int o = 1; o < 64; o <<= 1) { o0 += __shfl_xor(o0, o, 64); o1 += __shfl_xor(o1, o, 64); }
    if (lane == 0) { out[0] = o0 + bb[0]; out[1] = o1 + bb[1]; }
}

__global__ void zerok(float* p, int n)
{
    int i = blockIdx.x * 256 + threadIdx.x;
    if (i < n) p[i] = 0.f;
}
__global__ void zero2k(float* p) { p[0] = 0.f; p[1] = 0.f; }
__global__ void copy512(float* dst, const float* src)
{
    int i = blockIdx.x * 256 + threadIdx.x;
    if (i < 512) dst[i] = src[i];
}
__global__ void cast_bf16(const float* __restrict__ src, u16* __restrict__ dst, int n)
{
    int i = (blockIdx.x * 256 + threadIdx.x) * 4;
    if (i >= n) return;
    float4 v = *(const float4*)(src + i);
    dst[i + 0] = f2b(v.x); dst[i + 1] = f2b(v.y);
    dst[i + 2] = f2b(v.z); dst[i + 3] = f2b(v.w);
}
// dst[b][c][r] = src[b][r][c]  (cast-transpose fp32 RxC -> bf16 CxR)
__global__ void castT(const float* __restrict__ src, u16* __restrict__ dst,
                      int R, int C, int nb)
{
    size_t idx = (size_t)blockIdx.x * 256 + threadIdx.x;
    size_t tot = (size_t)R * C * nb;
    if (idx >= tot) return;
    int rc = R * C;
    int b = (int)(idx / rc);
    int rem = (int)(idx - (size_t)b * rc);
    int c = rem / R, r = rem - c * R;
    dst[idx] = f2b(src[(size_t)b * rc + (size_t)r * C + c]);
}

// ---------------------------------------------------------------------------
extern "C" void kernel_launch(void* const* d_in, const int* in_sizes, int n_in,
                              void* d_out, int out_size, void* d_ws, size_t ws_size,
                              hipStream_t stream)
{
    const float* h     = (const float*)d_in[0];
    const float* fc1_w = (const float*)d_in[1];
    const float* fc1_b = (const float*)d_in[2];
    const float* cls   = (const float*)d_in[3];
    bool sigorder = (in_sizes[10] == 512 * 49);
    int i_l2 = sigorder ? 16 : 10;
    int i_pp = sigorder ? 10 : 16;
    const float* l_g[2]   = { (const float*)d_in[4], (const float*)d_in[i_l2 + 0] };
    const float* l_b[2]   = { (const float*)d_in[5], (const float*)d_in[i_l2 + 1] };
    const float* l_qkv[2] = { (const float*)d_in[6], (const float*)d_in[i_l2 + 2] };
    const float* l_ow[2]  = { (const float*)d_in[7], (const float*)d_in[i_l2 + 3] };
    const float* l_ob[2]  = { (const float*)d_in[8], (const float*)d_in[i_l2 + 4] };
    const float* l_rw[2]  = { (const float*)d_in[9], (const float*)d_in[i_l2 + 5] };
    const float* w7 = (const float*)d_in[i_pp + 0];
    const float* b7 = (const float*)d_in[i_pp + 1];
    const float* w5 = (const float*)d_in[i_pp + 2];
    const float* b5 = (const float*)d_in[i_pp + 3];
    const float* w3 = (const float*)d_in[i_pp + 4];
    const float* b3 = (const float*)d_in[i_pp + 5];
    const float* ng   = (const float*)d_in[22];
    const float* nbv  = (const float*)d_in[23];
    const float* fc2w = (const float*)d_in[24];
    const float* fc2b = (const float*)d_in[25];
    float* out = (float*)d_out;

    char* Wb = (char*)d_ws;
    size_t off = 0;
    auto allocB = [&](size_t bytes) { void* p = Wb + off; off = (off + bytes + 255) & ~(size_t)255; return p; };

    float* SEQ   = (float*)allocB((size_t)NSEQ * 512 * 4);
    float* XP    = (float*)allocB((size_t)LPAD * 512 * 4);
    u16*   XPh   = (u16*)  allocB((size_t)LPAD * 512 * 2);
    u16*   QKVh  = (u16*)  allocB((size_t)LPAD * 1536 * 2);
    float* QLKL  = (float*)allocB((size_t)262144 * 4);
    float* QL = QLKL, *KL = QLKL + 131072;
    u16*   QLKLh = (u16*)  allocB((size_t)262144 * 2);
    u16*   QLh = QLKLh, *KLh = QLKLh + 131072;
    float* A2   = (float*)allocB(524288 * 4);
    u16*   A2h  = (u16*)  allocB(524288 * 2);
    float* Zf0  = (float*)allocB(524288 * 4);
    float* Zf1  = (float*)allocB(524288 * 4);
    float* ZTf0 = (float*)allocB(524288 * 4);
    float* ZTf1 = (float*)allocB(524288 * 4);
    u16*   Zh0  = (u16*)  allocB(524288 * 2);
    u16*   Zh1  = (u16*)  allocB(524288 * 2);
    u16*   ZT0  = (u16*)  allocB(524288 * 2);
    u16*   ZT1  = (u16*)  allocB(524288 * 2);
    float* XZf  = (float*)allocB(524288 * 4);
    float* XZTf = (float*)allocB(524288 * 4);
    u16*   xzh  = (u16*)  allocB(524288 * 2);
    u16*   xzTh = (u16*)  allocB(524288 * 2);
    u16*   w2Th = (u16*)  allocB(524288 * 2);
    u16*   w3Th = (u16*)  allocB(524288 * 2);
    float* W2b  = (float*)allocB(524288 * 4);
    float* W3b  = (float*)allocB(524288 * 4);
    float* A3V  = (float*)allocB(131072 * 4);
    float* ZMATf= (float*)allocB(131072 * 4);
    u16*   ZMATt= (u16*)  allocB(131072 * 2);
    u16*   Vt   = (u16*)  allocB((size_t)8 * 64 * LPAD * 2);
    u16*   fc1wt= (u16*)  allocB(524288 * 2);
    u16*   qkvwt= (u16*)  allocB(786432 * 2);
    u16*   outwt= (u16*)  allocB(262144 * 2);
    float* W49  = (float*)allocB(49 * 512 * 4);
    float* BSUM = (float*)allocB(512 * 4);
    float* SCAL = (float*)allocB(16);
    void*  U1   = allocB((size_t)LPAD * 512 * 4);
    u16*   hbf  = (u16*)U1;
    float* OUT  = (float*)U1;
    float* SEQ2 = OUT;
    size_t fixed = off;

    size_t scB_b = (size_t)8 * 256 * LPAD * 4;
    size_t phB_b = (size_t)8 * 256 * LPAD * 2;
    bool batched = ws_size >= fixed + scB_b + phB_b;
    float* SC; u16* Ph;
    if (batched) {
        SC = (float*)(Wb + fixed);
        Ph = (u16*)(Wb + fixed + scB_b);
    } else {
        SC = (float*)(Wb + fixed);
        Ph = (u16*)(Wb + fixed + (size_t)256 * LPAD * 4);
    }
    u16* OUTh = (u16*)SC;

    auto mgemm = [&](const u16* A, int lda, long sA, const u16* Bt, int ldb, long sB,
                     void* C, int ldc, long sC, int M, int N, int K,
                     const float* bias, const float* resid, int ldr,
                     int relu, int qscale, int obf16, int nbatch, int ksplit, int atomic) {
        dim3 grid((N + 127) / 128, (M + 127) / 128, nbatch * ksplit);
        gemm_mfma<<<grid, 256, 0, stream>>>(A, lda, sA, Bt, ldb, sB, C, ldc, sC,
            M, N, K, ksplit, bias, resid, ldr, relu, qscale, obf16, atomic);
    };
    auto fgemm = [&](const float* A, int lda, long sA, const float* B, int ldb, long sB,
                     float* C, int ldc, long sC, int M, int N, int K,
                     float alpha, float diagc, const float* bias,
                     const float* resid, int ldr, long sR, float rescoef,
                     int btrans, int nbatch) {
        dim3 grid(N / 64, (M + 63) / 64, nbatch);
        gemm_big<<<grid, 256, 0, stream>>>(A, lda, sA, B, ldb, sB, C, ldc, sC, M, N, K,
            alpha, diagc, bias, resid, ldr, sR, rescoef, btrans);
    };
    auto ns1 = [&](const u16* A, const u16* B, const float* r, float al, float be,
                   float* Cf, u16* Ch) {
        ns_gemm<<<dim3(2, 2, 8), 256, 0, stream>>>(A, B, r, al, be, Cf, Ch,
                                                   A, B, r, al, be, Cf, Ch);
    };
    auto ns2 = [&](const u16* A0, const u16* B0, const float* r0, float al0, float be0,
                   float* Cf0, u16* Ch0,
                   const u16* A1, const u16* B1, const float* r1, float al1, float be1,
                   float* Cf1, u16* Ch1) {
        ns_gemm<<<dim3(2, 2, 16), 256, 0, stream>>>(A0, B0, r0, al0, be0, Cf0, Ch0,
                                                    A1, B1, r1, al1, be1, Cf1, Ch1);
    };

    // ---- prologue
    cast_bf16<<<(NPIX * 1024 / 4 + 255) / 256, 256, 0, stream>>>(h, hbf, NPIX * 1024);
    castT<<<(524288 + 255) / 256, 256, 0, stream>>>(fc1_w, fc1wt, 1024, 512, 1);
    mgemm(hbf, 1024, 0, fc1wt, 1024, 0, SEQ + 512, 512, 0, NPIX, 512, 1024,
          fc1_b, nullptr, 0, 1, 0, 0, 1, 1, 0);
    copy512<<<2, 256, 0, stream>>>(SEQ, cls);
    zerok<<<(PADT * 512 + 255) / 256, 256, 0, stream>>>(XP, PADT * 512);
    zerok<<<(PADT * 256 + 255) / 256, 256, 0, stream>>>((float*)XPh, PADT * 256);
    ppeg_combine<<<(49 * 512 + 255) / 256, 256, 0, stream>>>(w7, w5, w3, b7, b5, b3, W49, BSUM);

    for (int layer = 0; layer < 2; layer++) {
        const float* curSEQ = (layer == 0) ? SEQ : SEQ2;
        ln_kernel<<<(NSEQ + 3) / 4, 256, 0, stream>>>(curSEQ, XP + (size_t)PADT * 512,
            XPh + (size_t)PADT * 512, l_g[layer], l_b[layer], NSEQ);
        castT<<<(786432 + 255) / 256, 256, 0, stream>>>(l_qkv[layer], qkvwt, 512, 1536, 1);
        mgemm(XPh, 512, 0, qkvwt, 512, 0, QKVh, 1536, 0, LPAD, 1536, 512,
              nullptr, nullptr, 0, 0, 1, 1, 1, 1, 0);
        landmarks_kernel<<<dim3(256, 8), 64, 0, stream>>>(QKVh, QL, KL, QLh, KLh);
        // a2 = softmax(ql @ kl^T)  (fp32)
        fgemm(QL, 64, 16384, KL, 64, 16384, A2, 256, 65536, 256, 256, 64,
              1.f, 0.f, nullptr, nullptr, 0, 0, 0.f, 1, 8);
        softmax_a2<<<512, 256, 0, stream>>>(A2, A2h, 2048);
        zero2k<<<1, 1, 0, stream>>>(SCAL);
        a2norms_kernel<<<8, 256, 0, stream>>>(A2, SCAL);
        z0_kernel<<<dim3(256, 8), 256, 0, stream>>>(A2, SCAL, Zf0, ZTf0, Zh0, ZT0);

        // Newton-Schulz: 5 bf16 MFMA iterations (paired transposed-product
        // formulation, all outputs coalesced row-major) + 1 fp32 polish.
        float* zcf = Zf0;  float* zcTf = ZTf0;  u16* zch = Zh0;  u16* zcTh = ZT0;
        float* znf = Zf1;  float* znTf = ZTf1;  u16* znh = Zh1;  u16* znTh = ZT1;
        for (int it = 0; it < 5; it++) {
            // XZ = A2@Z (bf16 out) ; XZ^T = Z^T@A2^T (fp32+bf16 out)
            ns2(A2h, zcTh, nullptr, 1.f, 0.f, nullptr, xzh,
                zcTh, A2h, nullptr, 1.f, 0.f, XZTf, xzTh);
            // W2^T = 7*XZ^T - XZ^T@XZ^T
            ns1(xzTh, xzh, XZTf, -1.f, 7.f, nullptr, w2Th);
            // W3^T = 15*XZ^T - W2^T@XZ^T
            ns1(w2Th, xzh, XZTf, -1.f, 15.f, nullptr, w3Th);
            // Z' = 3.25Z - 0.25 Z@W3 ; Z'^T = 3.25Z^T - 0.25 W3^T@Z^T
            ns2(zch, w3Th, zcf, -0.25f, 3.25f, znf, znh,
                w3Th, zch, zcTf, -0.25f, 3.25f, znTf, znTh);
            float* t;
            t = zcf;  zcf = znf;  znf = t;
            t = zcTf; zcTf = znTf; znTf = t;
            u16* u;
            u = zch;  zch = znh;  znh = u;
            u = zcTh; zcTh = znTh; znTh = u;
        }
        // fp32 polish: zn = 0.25 zc (13I - XZ(15I - XZ(7I - XZ)))
        fgemm(A2, 256, 65536, zcf, 256, 65536, XZf, 256, 65536, 256, 256, 256,
              1.f, 0.f, nullptr, nullptr, 0, 0, 0.f, 0, 8);
        fgemm(XZf, 256, 65536, XZf, 256, 65536, W2b, 256, 65536, 256, 256, 256,
              1.f, 15.f, nullptr, XZf, 256, 65536, -7.f, 0, 8);
        fgemm(XZf, 256, 65536, W2b, 256, 65536, W3b, 256, 65536, 256, 256, 256,
              -1.f, 13.f, nullptr, nullptr, 0, 0, 0.f, 0, 8);
        fgemm(zcf, 256, 65536, W3b, 256, 65536, znf, 256, 65536, 256, 256, 256,
              0.25f, 0.f, nullptr, nullptr, 0, 0, 0.f, 0, 8);
        float* zfin = znf;

        // a3v = softmax(ql @ k^T) @ v  via MFMA
        vtrans<<<dim3(160, 8), 256, 0, stream>>>(QKVh, Vt);
        zerok<<<512, 256, 0, stream>>>(A3V, 131072);
        if (batched) {
            mgemm(QLh, 64, 16384, QKVh + 512, 1536, 64, SC, LPAD, (long)256 * LPAD,
                  256, LPAD, 64, nullptr, nullptr, 0, 0, 0, 0, 8, 1, 0);
            row_softmax_bf16<<<2048, 256, 0, stream>>>(SC, Ph, LPAD);
            mgemm(Ph, LPAD, (long)256 * LPAD, Vt, LPAD, (long)64 * LPAD, A3V, 64, 16384,
                  256, 64, LPAD, nullptr, nullptr, 0, 0, 0, 0, 8, 40, 1);
        } else {
            for (int hh = 0; hh < 8; hh++) {
                mgemm(QLh + (size_t)hh * 16384, 64, 0, QKVh + 512 + hh * 64, 1536, 0,
                      SC, LPAD, 0, 256, LPAD, 64, nullptr, nullptr, 0, 0, 0, 0, 1, 1, 0);
                row_softmax_bf16<<<256, 256, 0, stream>>>(SC, Ph, LPAD);
                mgemm(Ph, LPAD, 0, Vt + (size_t)hh * 64 * LPAD, LPAD, 0,
                      A3V + (size_t)hh * 16384, 64, 0, 256, 64, LPAD,
                      nullptr, nullptr, 0, 0, 0, 0, 1, 40, 1);
            }
        }
        // ZMAT = pinv(a2) @ a3v  (fp32)
        fgemm(zfin, 256, 65536, A3V, 64, 16384, ZMATf, 64, 16384, 256, 64, 256,
              1.f, 0.f, nullptr, nullptr, 0, 0, 0.f, 0, 8);

        if (layer == 0) {
            castT<<<(131072 + 255) / 256, 256, 0, stream>>>(ZMATf, ZMATt, 256, 64, 8);
            if (batched) {
                mgemm(QKVh, 1536, 64, KLh, 64, 16384, SC, 256, (long)LPAD * 256,
                      LPAD, 256, 64, nullptr, nullptr, 0, 0, 0, 0, 8, 1, 0);
                softmax256_bf16<<<8 * LPAD / 4, 256, 0, stream>>>(SC, Ph, 8 * LPAD);
                mgemm(Ph, 256, (long)LPAD * 256, ZMATt, 256, 16384, OUT, 512, 64,
                      LPAD, 64, 256, nullptr, nullptr, 0, 0, 0, 0, 8, 1, 0);
            } else {
                for (int hh = 0; hh < 8; hh++) {
                    mgemm(QKVh + hh * 64, 1536, 0, KLh + (size_t)hh * 16384, 64, 0,
                          SC, 256, 0, LPAD, 256, 64, nullptr, nullptr, 0, 0, 0, 0, 1, 1, 0);
                    softmax256_bf16<<<LPAD / 4, 256, 0, stream>>>(SC, Ph, LPAD);
                    mgemm(Ph, 256, 0, ZMATt + (size_t)hh * 16384, 256, 0,
                          OUT + hh * 64, 512, 0, LPAD, 64, 256,
                          nullptr, nullptr, 0, 0, 0, 0, 1, 1, 0);
                }
            }
            conv_res<<<(NSEQ * 512 + 255) / 256, 256, 0, stream>>>(QKVh, OUT, l_rw[0], PADT, NSEQ);
            cast_bf16<<<(NSEQ * 512 / 4 + 255) / 256, 256, 0, stream>>>(
                OUT + (size_t)PADT * 512, OUTh, NSEQ * 512);
            castT<<<(262144 + 255) / 256, 256, 0, stream>>>(l_ow[0], outwt, 512, 512, 1);
            mgemm(OUTh, 512, 0, outwt, 512, 0, SEQ, 512, 0, NSEQ, 512, 512,
                  l_ob[0], XP + (size_t)PADT * 512, 512, 0, 0, 0, 1, 1, 0);
            // PPEG
            ppeg_fast<<<dim3(10000, 2), 256, 0, stream>>>(SEQ, SEQ2, W49, BSUM);
            copy512<<<2, 256, 0, stream>>>(SEQ2, SEQ);
        } else {
            a1z_single<<<8, 256, 0, stream>>>(QKVh, KL, ZMATf, OUT, PADT);
            conv_res<<<2, 256, 0, stream>>>(QKVh, OUT, l_rw[1], PADT, 1);
            fgemm(OUT + (size_t)PADT * 512, 512, 0, l_ow[1], 512, 0, SEQ, 512, 0,
                  1, 512, 512, 1.f, 0.f, l_ob[1],
                  XP + (size_t)PADT * 512, 512, 0, 1.f, 0, 1);
        }
    }
    final_kernel<<<1, 64, 0, stream>>>(SEQ, ng, nbv, fc2w, fc2b, out);
    (void)n_in; (void)out_size;
}

// Round 7
// 2004.146 us; speedup vs baseline: 1.6921x; 1.5313x over previous
//
#include <hip/hip_runtime.h>
#include <math.h>

#define LPAD  10240
#define NSEQ  10001
#define PADT  239
#define NPIX  10000

typedef unsigned short u16;
typedef __attribute__((ext_vector_type(8))) short short8;
typedef __attribute__((ext_vector_type(4))) float floatx4;

__device__ __forceinline__ float b2f(u16 u){ return __uint_as_float(((unsigned)u)<<16); }
__device__ __forceinline__ u16 f2b(float f){
    unsigned x = __float_as_uint(f);
    return (u16)((x + 0x7FFFu + ((x>>16)&1u)) >> 16);
}
__device__ __forceinline__ void gld16(const void* g, void* l){
    __builtin_amdgcn_global_load_lds(
        (const __attribute__((address_space(1))) unsigned int*)g,
        (__attribute__((address_space(3))) unsigned int*)l, 16, 0, 0);
}

// ---------------------------------------------------------------------------
// bf16 MFMA GEMM: C = A @ Bt^T (+bias)(+resid)(relu)(qscale). A: M x K bf16
// row-major (lda, batch sA). Bt: N x K bf16 (ldb, sB). C fp32 or bf16 (obf16),
// 128x128 tile, 4 waves, 16x16x32 MFMA, global_load_lds width-16 staging.
// ---------------------------------------------------------------------------
__global__ __launch_bounds__(256) void gemm_mfma(
    const u16* __restrict__ A, int lda, long sA,
    const u16* __restrict__ Bt, int ldb, long sB,
    void* __restrict__ Cv, int ldc, long sC,
    int M, int N, int K, int ksplit,
    const float* __restrict__ bias,
    const float* __restrict__ resid, int ldr,
    int relu, int qscale, int obf16, int atomic)
{
    __shared__ u16 As[128*32];
    __shared__ u16 Bs[128*32];

    int bz = blockIdx.z / ksplit;
    int ks = blockIdx.z - bz * ksplit;
    A  += (size_t)bz * sA;
    Bt += (size_t)bz * sB;

    int kchunk = (K + ksplit - 1) / ksplit;
    kchunk = (kchunk + 31) & ~31;
    int kbeg = ks * kchunk;
    int kend = kbeg + kchunk; if (kend > K) kend = K;

    int tid = threadIdx.x;
    int w = tid >> 6, lane = tid & 63;
    int wm = (w >> 1) * 64, wn = (w & 1) * 64;
    int m0 = blockIdx.y * 128, n0 = blockIdx.x * 128;

    int l4 = lane >> 2;
    int lk = (lane & 3) * 8;
    int r0 = w * 32 + l4;
    int am0 = m0 + r0;      if (am0 > M-1) am0 = M-1;
    int am1 = m0 + r0 + 16; if (am1 > M-1) am1 = M-1;
    int bn0 = n0 + r0;      if (bn0 > N-1) bn0 = N-1;
    int bn1 = n0 + r0 + 16; if (bn1 > N-1) bn1 = N-1;
    const u16* ag0 = A  + (size_t)am0 * lda + lk;
    const u16* ag1 = A  + (size_t)am1 * lda + lk;
    const u16* bg0 = Bt + (size_t)bn0 * ldb + lk;
    const u16* bg1 = Bt + (size_t)bn1 * ldb + lk;
    u16* sa0 = &As[(w*32)      * 32];
    u16* sa1 = &As[(w*32 + 16) * 32];
    u16* sb0 = &Bs[(w*32)      * 32];
    u16* sb1 = &Bs[(w*32 + 16) * 32];

    floatx4 acc[4][4];
    #pragma unroll
    for (int i = 0; i < 4; i++)
        #pragma unroll
        for (int j = 0; j < 4; j++)
            acc[i][j] = (floatx4){0.f, 0.f, 0.f, 0.f};

    int arow = wm + (lane & 15);
    int nrow = wn + (lane & 15);
    int koff = (lane >> 4) * 8;

    for (int k0 = kbeg; k0 < kend; k0 += 32) {
        gld16(ag0 + k0, sa0);
        gld16(ag1 + k0, sa1);
        gld16(bg0 + k0, sb0);
        gld16(bg1 + k0, sb1);
        __syncthreads();
        short8 af[4], bf[4];
        #pragma unroll
        for (int i = 0; i < 4; i++) af[i] = *(const short8*)&As[(arow + i*16)*32 + koff];
        #pragma unroll
        for (int j = 0; j < 4; j++) bf[j] = *(const short8*)&Bs[(nrow + j*16)*32 + koff];
        #pragma unroll
        for (int i = 0; i < 4; i++)
            #pragma unroll
            for (int j = 0; j < 4; j++)
                acc[i][j] = __builtin_amdgcn_mfma_f32_16x16x32_bf16(af[i], bf[j], acc[i][j], 0, 0, 0);
        __syncthreads();
    }

    float* Cf = (float*)Cv;
    u16*   Ch = (u16*)Cv;
    size_t cb = (size_t)bz * sC;
    int rbase = m0 + wm + (lane >> 4) * 4;
    int cbase = n0 + wn + (lane & 15);
    #pragma unroll
    for (int i = 0; i < 4; i++) {
        #pragma unroll
        for (int j = 0; j < 4; j++) {
            int col = cbase + j * 16;
            if (col >= N) continue;
            float bcol = bias ? bias[col] : 0.f;
            #pragma unroll
            for (int r = 0; r < 4; r++) {
                int row = rbase + i * 16 + r;
                if (row >= M) continue;
                float v = acc[i][j][r];
                if (qscale && col < 512) v *= 0.125f;
                v += bcol;
                if (resid) v += resid[(size_t)row * ldr + col];
                if (relu) v = fmaxf(v, 0.f);
                size_t ci = cb + (size_t)row * ldc + col;
                if (obf16) Ch[ci] = f2b(v);
                else if (atomic) atomicAdd(&Cf[ci], v);
                else Cf[ci] = v;
            }
        }
    }
}

// ---------------------------------------------------------------------------
// fp32 tiled GEMM (Newton-Schulz chain + tiny gemms).
// C = alpha*A@B + diagc*I + bias + rescoef*resid.
// ---------------------------------------------------------------------------
__global__ __launch_bounds__(256) void gemm_big(
    const float* __restrict__ A, int lda, long sA,
    const float* __restrict__ B, int ldb, long sB,
    float* __restrict__ C, int ldc, long sC,
    int M, int N, int K,
    float alpha, float diagc,
    const float* __restrict__ bias,
    const float* __restrict__ resid, int ldr, long sR, float rescoef,
    int btrans)
{
    __shared__ float As[16][68];
    __shared__ float Bs[16][64];

    int bz = blockIdx.z;
    A += (size_t)bz * sA;
    B += (size_t)bz * sB;
    C += (size_t)bz * sC;

    int tid = threadIdx.x;
    int tx = tid & 15, ty = tid >> 4;
    int m0 = blockIdx.y * 64, n0 = blockIdx.x * 64;

    float acc[4][4];
    #pragma unroll
    for (int i = 0; i < 4; i++)
        #pragma unroll
        for (int j = 0; j < 4; j++) acc[i][j] = 0.f;

    for (int k0 = 0; k0 < K; k0 += 16) {
        {
            int r = tid >> 2;
            int kk = (tid & 3) * 4;
            int m = m0 + r;
            float4 av = make_float4(0.f, 0.f, 0.f, 0.f);
            if (m < M) av = *(const float4*)(A + (size_t)m * lda + k0 + kk);
            As[kk + 0][r] = av.x; As[kk + 1][r] = av.y;
            As[kk + 2][r] = av.z; As[kk + 3][r] = av.w;
        }
        if (!btrans) {
            int r = tid >> 6;
            int c = tid & 63;
            #pragma unroll
            for (int i = 0; i < 4; i++) {
                int kk = r + i * 4;
                Bs[kk][c] = B[(size_t)(k0 + kk) * ldb + n0 + c];
            }
        } else {
            int c = tid >> 2;
            int kk = (tid & 3) * 4;
            float4 bv = *(const float4*)(B + (size_t)(n0 + c) * ldb + k0 + kk);
            Bs[kk + 0][c] = bv.x; Bs[kk + 1][c] = bv.y;
            Bs[kk + 2][c] = bv.z; Bs[kk + 3][c] = bv.w;
        }
        __syncthreads();
        #pragma unroll
        for (int k = 0; k < 16; k++) {
            float4 a4 = *(const float4*)&As[k][ty * 4];
            float4 b4 = *(const float4*)&Bs[k][tx * 4];
            float a[4] = {a4.x, a4.y, a4.z, a4.w};
            float b[4] = {b4.x, b4.y, b4.z, b4.w};
            #pragma unroll
            for (int i = 0; i < 4; i++)
                #pragma unroll
                for (int j = 0; j < 4; j++) acc[i][j] += a[i] * b[j];
        }
        __syncthreads();
    }

    #pragma unroll
    for (int i = 0; i < 4; i++) {
        int m = m0 + ty * 4 + i;
        if (m >= M) continue;
        #pragma unroll
        for (int j = 0; j < 4; j++) {
            int n = n0 + tx * 4 + j;
            float v = alpha * acc[i][j];
            if (diagc != 0.f && m == n) v += diagc;
            if (bias) v += bias[n];
            if (resid) v += rescoef * resid[(size_t)bz * sR + (size_t)m * ldr + n];
            C[(size_t)m * ldc + n] = v;
        }
    }
}

// ---------------------------------------------------------------------------
// Fused a1 chain (layer 0): per (64-token, head) block:
//   S = Q(64x64) @ KL^T(256x64)  [MFMA, fragments direct from L2]
//   P = row-softmax(S)           [cross-wave stats via LDS]
//   O = P @ Z                    [P in LDS (pad 264), Z^T fragments from L2]
// Writes OUT[tok][h*64+d] fp32 (full overwrite).
// ---------------------------------------------------------------------------
__global__ __launch_bounds__(256) void a1z_fused(
    const u16* __restrict__ QKVh, const u16* __restrict__ KLh,
    const u16* __restrict__ ZTh, float* __restrict__ OUT, int T0)
{
    __shared__ u16 Ps[64 * 264];
    __shared__ float red[2][4][64];

    int tid = threadIdx.x;
    int w = tid >> 6, lane = tid & 63;
    int lo = lane & 15, hi = lane >> 4;
    int koff = hi * 8;
    int hh = blockIdx.y;
    int tok0 = T0 + blockIdx.x * 64;

    // ---- scores: wave w covers landmark cols [w*64, w*64+64)
    floatx4 acc[4][4];
    #pragma unroll
    for (int i = 0; i < 4; i++)
        #pragma unroll
        for (int j = 0; j < 4; j++)
            acc[i][j] = (floatx4){0.f, 0.f, 0.f, 0.f};

    #pragma unroll
    for (int ks = 0; ks < 2; ks++) {
        short8 aq[4], bk[4];
        #pragma unroll
        for (int i = 0; i < 4; i++) {
            int tok = tok0 + i * 16 + lo; if (tok > LPAD - 1) tok = LPAD - 1;
            aq[i] = *(const short8*)(QKVh + (size_t)tok * 1536 + hh * 64 + ks * 32 + koff);
        }
        #pragma unroll
        for (int j = 0; j < 4; j++) {
            int nr = w * 64 + j * 16 + lo;
            bk[j] = *(const short8*)(KLh + ((size_t)hh * 256 + nr) * 64 + ks * 32 + koff);
        }
        #pragma unroll
        for (int i = 0; i < 4; i++)
            #pragma unroll
            for (int j = 0; j < 4; j++)
                acc[i][j] = __builtin_amdgcn_mfma_f32_16x16x32_bf16(aq[i], bk[j], acc[i][j], 0, 0, 0);
    }

    // ---- per-wave softmax stats (rows split across lane&15 groups)
    #pragma unroll
    for (int i = 0; i < 4; i++) {
        #pragma unroll
        for (int slot = 0; slot < 4; slot++) {
            float mx = acc[i][0][slot];
            mx = fmaxf(mx, acc[i][1][slot]);
            mx = fmaxf(mx, acc[i][2][slot]);
            mx = fmaxf(mx, acc[i][3][slot]);
            mx = fmaxf(mx, __shfl_xor(mx, 1, 64));
            mx = fmaxf(mx, __shfl_xor(mx, 2, 64));
            mx = fmaxf(mx, __shfl_xor(mx, 4, 64));
            mx = fmaxf(mx, __shfl_xor(mx, 8, 64));
            float sm = __expf(acc[i][0][slot] - mx) + __expf(acc[i][1][slot] - mx)
                     + __expf(acc[i][2][slot] - mx) + __expf(acc[i][3][slot] - mx);
            sm += __shfl_xor(sm, 1, 64);
            sm += __shfl_xor(sm, 2, 64);
            sm += __shfl_xor(sm, 4, 64);
            sm += __shfl_xor(sm, 8, 64);
            if (lo == 0) {
                int row = i * 16 + hi * 4 + slot;
                red[0][w][row] = mx;
                red[1][w][row] = sm;
            }
        }
    }
    __syncthreads();

    // ---- final probs -> Ps (bf16, 264-padded rows)
    #pragma unroll
    for (int i = 0; i < 4; i++) {
        #pragma unroll
        for (int slot = 0; slot < 4; slot++) {
            int row = i * 16 + hi * 4 + slot;
            float l0 = red[0][0][row], l1 = red[0][1][row];
            float l2 = red[0][2][row], l3 = red[0][3][row];
            float M = fmaxf(fmaxf(l0, l1), fmaxf(l2, l3));
            float T = red[1][0][row] * __expf(l0 - M) + red[1][1][row] * __expf(l1 - M)
                    + red[1][2][row] * __expf(l2 - M) + red[1][3][row] * __expf(l3 - M);
            float inv = 1.f / T;
            #pragma unroll
            for (int j = 0; j < 4; j++)
                Ps[row * 264 + w * 64 + j * 16 + lo] = f2b(__expf(acc[i][j][slot] - M) * inv);
        }
    }
    __syncthreads();

    // ---- PV: wave w computes rows [w*16, w*16+16), K=256
    floatx4 acc2[4];
    #pragma unroll
    for (int j = 0; j < 4; j++) acc2[j] = (floatx4){0.f, 0.f, 0.f, 0.f};
    #pragma unroll
    for (int ks = 0; ks < 8; ks++) {
        short8 ap = *(const short8*)&Ps[(w * 16 + lo) * 264 + ks * 32 + koff];
        #pragma unroll
        for (int j = 0; j < 4; j++) {
            short8 bz = *(const short8*)(ZTh + ((size_t)hh * 64 + j * 16 + lo) * 256 + ks * 32 + koff);
            acc2[j] = __builtin_amdgcn_mfma_f32_16x16x32_bf16(ap, bz, acc2[j], 0, 0, 0);
        }
    }
    #pragma unroll
    for (int j = 0; j < 4; j++) {
        #pragma unroll
        for (int slot = 0; slot < 4; slot++) {
            int tok = tok0 + w * 16 + hi * 4 + slot;
            if (tok < LPAD)
                OUT[(size_t)tok * 512 + hh * 64 + j * 16 + lo] = acc2[j][slot];
        }
    }
}

// ---------------------------------------------------------------------------
__global__ __launch_bounds__(256) void ln_kernel(
    const float* __restrict__ X, float* __restrict__ OUT, u16* __restrict__ OUTH,
    const float* __restrict__ g, const float* __restrict__ b, int nrows)
{
    int row = blockIdx.x * 4 + (threadIdx.x >> 6);
    int lane = threadIdx.x & 63;
    if (row >= nrows) return;
    const float* xr = X + (size_t)row * 512;
    float v[8]; float s = 0.f, s2 = 0.f;
    #pragma unroll
    for (int i = 0; i < 8; i++) { float t = xr[lane + i * 64]; v[i] = t; s += t; s2 += t * t; }
    for (int o = 1; o < 64; o <<= 1) { s += __shfl_xor(s, o, 64); s2 += __shfl_xor(s2, o, 64); }
    float mu = s * (1.f / 512.f);
    float var = s2 * (1.f / 512.f) - mu * mu;
    float rs = rsqrtf(var + 1e-5f);
    float* orow = OUT + (size_t)row * 512;
    u16* hrow = OUTH + (size_t)row * 512;
    #pragma unroll
    for (int i = 0; i < 8; i++) {
        int j = lane + i * 64;
        float y = (v[i] - mu) * rs * g[j] + b[j];
        orow[j] = y;
        hrow[j] = f2b(y);
    }
}

// Landmark means from bf16 QKVh; writes fp32 and bf16 copies
__global__ __launch_bounds__(64) void landmarks_kernel(
    const u16* __restrict__ QKVh, float* __restrict__ QL, float* __restrict__ KL,
    u16* __restrict__ QLh, u16* __restrict__ KLh)
{
    int mm = blockIdx.x, hh = blockIdx.y;
    int d = threadIdx.x;
    const u16* base = QKVh + (size_t)(mm * 40) * 1536 + hh * 64 + d;
    float sq = 0.f, sk = 0.f;
    for (int li = 0; li < 40; li++) {
        sq += b2f(base[(size_t)li * 1536]);
        sk += b2f(base[(size_t)li * 1536 + 512]);
    }
    size_t o = ((size_t)hh * 256 + mm) * 64 + d;
    float q = sq * (1.f / 40.f), k = sk * (1.f / 40.f);
    QL[o] = q; KL[o] = k;
    QLh[o] = f2b(q); KLh[o] = f2b(k);
}

// a2 softmax: wave per row (256 cols), fp32 in place
__global__ __launch_bounds__(256) void softmax_a2(
    float* __restrict__ A2, int nrows)
{
    int row = blockIdx.x * 4 + (threadIdx.x >> 6);
    int lane = threadIdx.x & 63;
    if (row >= nrows) return;
    float* p = A2 + (size_t)row * 256 + lane * 4;
    float4 v = *(float4*)p;
    float mx = fmaxf(fmaxf(v.x, v.y), fmaxf(v.z, v.w));
    for (int o = 1; o < 64; o <<= 1) mx = fmaxf(mx, __shfl_xor(mx, o, 64));
    float4 e = make_float4(__expf(v.x - mx), __expf(v.y - mx),
                           __expf(v.z - mx), __expf(v.w - mx));
    float s = e.x + e.y + e.z + e.w;
    for (int o = 1; o < 64; o <<= 1) s += __shfl_xor(s, o, 64);
    float inv = 1.f / s;
    e.x *= inv; e.y *= inv; e.z *= inv; e.w *= inv;
    *(float4*)p = e;
}

// block-per-row softmax (wide rows) -> bf16 probs
__global__ __launch_bounds__(256) void row_softmax_bf16(
    const float* __restrict__ S, u16* __restrict__ P, int ncols)
{
    int row = blockIdx.x;
    const float* p = S + (size_t)row * ncols;
    u16* q = P + (size_t)row * ncols;
    int tid = threadIdx.x;
    __shared__ float sr1[4], sr2[4];
    float mx = -1e30f;
    for (int i = tid; i < ncols; i += 256) mx = fmaxf(mx, p[i]);
    for (int o = 1; o < 64; o <<= 1) mx = fmaxf(mx, __shfl_xor(mx, o, 64));
    if ((tid & 63) == 0) sr1[tid >> 6] = mx;
    __syncthreads();
    mx = fmaxf(fmaxf(sr1[0], sr1[1]), fmaxf(sr1[2], sr1[3]));
    float s = 0.f;
    for (int i = tid; i < ncols; i += 256) s += __expf(p[i] - mx);
    for (int o = 1; o < 64; o <<= 1) s += __shfl_xor(s, o, 64);
    if ((tid & 63) == 0) sr2[tid >> 6] = s;
    __syncthreads();
    s = sr2[0] + sr2[1] + sr2[2] + sr2[3];
    float inv = 1.f / s;
    for (int i = tid; i < ncols; i += 256) q[i] = f2b(__expf(p[i] - mx) * inv);
}

__global__ __launch_bounds__(256) void a2norms_kernel(
    const float* __restrict__ A2, float* __restrict__ scal)
{
    int hh = blockIdx.x, tid = threadIdx.x;
    const float* A = A2 + (size_t)hh * 65536;
    float rs = 0.f, cs = 0.f;
    for (int j = 0; j < 256; j++) {
        rs += fabsf(A[(size_t)tid * 256 + j]);
        cs += fabsf(A[(size_t)j * 256 + tid]);
    }
    __shared__ float sm[8];
    for (int o = 1; o < 64; o <<= 1) {
        rs = fmaxf(rs, __shfl_xor(rs, o, 64));
        cs = fmaxf(cs, __shfl_xor(cs, o, 64));
    }
    if ((tid & 63) == 0) { sm[tid >> 6] = rs; sm[4 + (tid >> 6)] = cs; }
    __syncthreads();
    if (tid == 0) {
        float rm = fmaxf(fmaxf(sm[0], sm[1]), fmaxf(sm[2], sm[3]));
        float cm = fmaxf(fmaxf(sm[4], sm[5]), fmaxf(sm[6], sm[7]));
        atomicMax((unsigned int*)&scal[0], __float_as_uint(rm));
        atomicMax((unsigned int*)&scal[1], __float_as_uint(cm));
    }
}

// z0 = a2^T / denom (fp32 only)
__global__ __launch_bounds__(256) void z0_kernel(
    const float* __restrict__ A2, const float* __restrict__ scal,
    float* __restrict__ Zf)
{
    int i = blockIdx.x, hh = blockIdx.y, j = threadIdx.x;
    float inv = 1.f / (scal[0] * scal[1]);
    Zf[((size_t)hh * 256 + i) * 256 + j] = A2[((size_t)hh * 256 + j) * 256 + i] * inv;
}

// Tiny fused a1@Z for layer 1 (single token)
__global__ __launch_bounds__(256) void a1z_single(
    const u16* __restrict__ QKVh, const float* __restrict__ KL,
    const float* __restrict__ ZM, float* __restrict__ OUT, int tok)
{
    int h = blockIdx.x, tid = threadIdx.x;
    __shared__ float q[64];
    __shared__ float p[256];
    __shared__ float red[4];
    if (tid < 64) q[tid] = b2f(QKVh[(size_t)tok * 1536 + h * 64 + tid]);
    __syncthreads();
    const float* kl = KL + ((size_t)h * 256 + tid) * 64;
    float s = 0.f;
    for (int d = 0; d < 64; d++) s += q[d] * kl[d];
    float mx = s;
    for (int o = 1; o < 64; o <<= 1) mx = fmaxf(mx, __shfl_xor(mx, o, 64));
    if ((tid & 63) == 0) red[tid >> 6] = mx;
    __syncthreads();
    mx = fmaxf(fmaxf(red[0], red[1]), fmaxf(red[2], red[3]));
    float e = __expf(s - mx);
    float sum = e;
    for (int o = 1; o < 64; o <<= 1) sum += __shfl_xor(sum, o, 64);
    __syncthreads();
    if ((tid & 63) == 0) red[tid >> 6] = sum;
    __syncthreads();
    sum = red[0] + red[1] + red[2] + red[3];
    p[tid] = e / sum;
    __syncthreads();
    if (tid < 64) {
        float a = 0.f;
        for (int j = 0; j < 256; j++) a += p[j] * ZM[((size_t)h * 256 + j) * 64 + tid];
        OUT[(size_t)tok * 512 + h * 64 + tid] = a;
    }
}

// Depthwise 33-tap token conv, LDS-tiled: 16 tokens/block, 48-row V window.
__global__ __launch_bounds__(256) void conv_res_t(
    const u16* __restrict__ QKVh, float* __restrict__ OUT,
    const float* __restrict__ resw, int T0, int ntok)
{
    __shared__ u16 Vw[48][512];
    __shared__ float ws[264];
    int tid = threadIdx.x;
    int t0 = T0 + blockIdx.x * 16;
    int wv = tid >> 6, lnn = tid & 63;
    for (int r = wv; r < 48; r += 4) {
        int ts = t0 - 16 + r;
        short8 v = (short8){0,0,0,0,0,0,0,0};
        if (ts >= 0 && ts < LPAD)
            v = *(const short8*)(QKVh + (size_t)ts * 1536 + 1024 + lnn * 8);
        *(short8*)&Vw[r][lnn * 8] = v;
    }
    if (tid < 264) ws[tid] = resw[tid];
    __syncthreads();

    int c0 = tid * 2;
    int h = c0 >> 6;
    float wreg[33];
    #pragma unroll
    for (int r = 0; r < 33; r++) wreg[r] = ws[h * 33 + r];

    #pragma unroll 1
    for (int tk = 0; tk < 16; tk++) {
        int tok = t0 + tk;
        if (tok >= T0 + ntok) break;
        float a0 = 0.f, a1 = 0.f;
        #pragma unroll
        for (int r = 0; r < 33; r++) {
            unsigned pv = *(const unsigned*)&Vw[tk + r][c0];
            a0 += wreg[r] * __uint_as_float(pv << 16);
            a1 += wreg[r] * __uint_as_float(pv & 0xFFFF0000u);
        }
        OUT[(size_t)tok * 512 + c0]     += a0;
        OUT[(size_t)tok * 512 + c0 + 1] += a1;
    }
}

// Old simple conv (layer 1, single token)
__global__ __launch_bounds__(256) void conv_res(
    const u16* __restrict__ QKVh, float* __restrict__ OUT,
    const float* __restrict__ resw, int t0, int ntok)
{
    int idx = blockIdx.x * 256 + threadIdx.x;
    if (idx >= ntok * 512) return;
    int tok = t0 + (idx >> 9);
    int c = idx & 511;
    int h = c >> 6;
    const u16* vbase = QKVh + 1024 + c;
    float acc = 0.f;
    #pragma unroll 1
    for (int r = 0; r < 33; r++) {
        int ts = tok - 16 + r;
        if (ts >= 0 && ts < LPAD)
            acc += resw[h * 33 + r] * b2f(vbase[(size_t)ts * 1536]);
    }
    OUT[(size_t)tok * 512 + c] += acc;
}

// V slice of QKVh -> Vt[h][d][t] (bf16)
__global__ __launch_bounds__(256) void vtrans(
    const u16* __restrict__ QKVh, u16* __restrict__ Vt)
{
    int t0 = blockIdx.x * 64, hh = blockIdx.y;
    __shared__ u16 tile[64][65];
    #pragma unroll
    for (int ii = 0; ii < 16; ii++) {
        int idx = threadIdx.x + ii * 256;
        int t = idx >> 6, d = idx & 63;
        tile[t][d] = QKVh[(size_t)(t0 + t) * 1536 + 1024 + hh * 64 + d];
    }
    __syncthreads();
    #pragma unroll
    for (int ii = 0; ii < 16; ii++) {
        int idx = threadIdx.x + ii * 256;
        int d = idx >> 6, t = idx & 63;
        Vt[((size_t)hh * 64 + d) * LPAD + t0 + t] = tile[t][d];
    }
}

// Combine PPEG weights: W49[tap][c] = w7 + w5(in range) + w3(in range)
__global__ void ppeg_combine(
    const float* __restrict__ w7, const float* __restrict__ w5,
    const float* __restrict__ w3, const float* __restrict__ b7,
    const float* __restrict__ b5, const float* __restrict__ b3,
    float* __restrict__ W49, float* __restrict__ BSUM)
{
    int idx = blockIdx.x * 256 + threadIdx.x;
    if (idx >= 49 * 512) return;
    int tap = idx >> 9, c = idx & 511;
    int dy = tap / 7 - 3, dx = tap % 7 - 3;
    float v = w7[c * 49 + tap];
    if (dy >= -2 && dy <= 2 && dx >= -2 && dx <= 2)
        v += w5[c * 25 + (dy + 2) * 5 + (dx + 2)];
    if (dy >= -1 && dy <= 1 && dx >= -1 && dx <= 1)
        v += w3[c * 9 + (dy + 1) * 3 + (dx + 1)];
    W49[tap * 512 + c] = v;
    if (tap == 0) BSUM[c] = b7[c] + b5[c] + b3[c];
}

// PPEG: one position per block, combined weights, interior fast path.
__global__ __launch_bounds__(256) void ppeg_fast(
    const float* __restrict__ S, float* __restrict__ O,
    const float* __restrict__ W49, const float* __restrict__ BSUM)
{
    int pos = blockIdx.x;
    int y = pos / 100, x = pos - y * 100;
    int c = blockIdx.y * 256 + threadIdx.x;
    const float* Sc = S + 512 + c;
    float acc = Sc[(size_t)pos * 512] + BSUM[c];
    if (y >= 3 && y < 97 && x >= 3 && x < 97) {
        for (int dy = -3; dy <= 3; dy++) {
            #pragma unroll
            for (int dx = -3; dx <= 3; dx++)
                acc += Sc[(size_t)(pos + dy * 100 + dx) * 512]
                     * W49[((dy + 3) * 7 + (dx + 3)) * 512 + c];
        }
    } else {
        for (int dy = -3; dy <= 3; dy++) {
            int yy = y + dy; if ((unsigned)yy >= 100u) continue;
            #pragma unroll
            for (int dx = -3; dx <= 3; dx++) {
                int xx = x + dx; if ((unsigned)xx >= 100u) continue;
                acc += Sc[(size_t)(yy * 100 + xx) * 512]
                     * W49[((dy + 3) * 7 + (dx + 3)) * 512 + c];
            }
        }
    }
    O[(size_t)(1 + pos) * 512 + c] = acc;
}

__global__ __launch_bounds__(64) void final_kernel(
    const float* __restrict__ S, const float* __restrict__ g, const float* __restrict__ b,
    const float* __restrict__ w, const float* __restrict__ bb, float* __restrict__ out)
{
    int lane = threadIdx.x;
    float v[8]; float s = 0.f, s2 = 0.f;
    #pragma unroll
    for (int i = 0; i < 8; i++) { float t = S[lane + i * 64]; v[i] = t; s += t; s2 += t * t; }
    for (int o = 1; o < 64; o <<= 1) { s += __shfl_xor(s, o, 64); s2 += __shfl_xor(s2, o, 64); }
    float mu = s * (1.f / 512.f);
    float var = s2 * (1.f / 512.f) - mu * mu;
    float rs = rsqrtf(var + 1e-5f);
    float o0 = 0.f, o1 = 0.f;
    #pragma unroll
    for (int i = 0; i < 8; i++) {
        int j = lane + i * 64;
        float xn = (v[i] - mu) * rs * g[j] + b[j];
        o0 += xn * w[j * 2 + 0];
        o1 += xn * w[j * 2 + 1];
    }
    for (int o = 1; o < 64; o <<= 1) { o0 += __shfl_xor(o0, o, 64); o1 += __shfl_xor(o1, o, 64); }
    if (lane == 0) { out[0] = o0 + bb[0]; out[1] = o1 + bb[1]; }
}

__global__ void zerok(float* p, int n)
{
    int i = blockIdx.x * 256 + threadIdx.x;
    if (i < n) p[i] = 0.f;
}
__global__ void zero2k(float* p) { p[0] = 0.f; p[1] = 0.f; }
__global__ void copy512(float* dst, const float* src)
{
    int i = blockIdx.x * 256 + threadIdx.x;
    if (i < 512) dst[i] = src[i];
}
__global__ void cast_bf16(const float* __restrict__ src, u16* __restrict__ dst, int n)
{
    int i = (blockIdx.x * 256 + threadIdx.x) * 4;
    if (i >= n) return;
    float4 v = *(const float4*)(src + i);
    dst[i + 0] = f2b(v.x); dst[i + 1] = f2b(v.y);
    dst[i + 2] = f2b(v.z); dst[i + 3] = f2b(v.w);
}
// dst[b][c][r] = src[b][r][c]  (cast-transpose fp32 RxC -> bf16 CxR)
__global__ void castT(const float* __restrict__ src, u16* __restrict__ dst,
                      int R, int C, int nb)
{
    size_t idx = (size_t)blockIdx.x * 256 + threadIdx.x;
    size_t tot = (size_t)R * C * nb;
    if (idx >= tot) return;
    int rc = R * C;
    int b = (int)(idx / rc);
    int rem = (int)(idx - (size_t)b * rc);
    int c = rem / R, r = rem - c * R;
    dst[idx] = f2b(src[(size_t)b * rc + (size_t)r * C + c]);
}

// ---------------------------------------------------------------------------
extern "C" void kernel_launch(void* const* d_in, const int* in_sizes, int n_in,
                              void* d_out, int out_size, void* d_ws, size_t ws_size,
                              hipStream_t stream)
{
    const float* h     = (const float*)d_in[0];
    const float* fc1_w = (const float*)d_in[1];
    const float* fc1_b = (const float*)d_in[2];
    const float* cls   = (const float*)d_in[3];
    bool sigorder = (in_sizes[10] == 512 * 49);
    int i_l2 = sigorder ? 16 : 10;
    int i_pp = sigorder ? 10 : 16;
    const float* l_g[2]   = { (const float*)d_in[4], (const float*)d_in[i_l2 + 0] };
    const float* l_b[2]   = { (const float*)d_in[5], (const float*)d_in[i_l2 + 1] };
    const float* l_qkv[2] = { (const float*)d_in[6], (const float*)d_in[i_l2 + 2] };
    const float* l_ow[2]  = { (const float*)d_in[7], (const float*)d_in[i_l2 + 3] };
    const float* l_ob[2]  = { (const float*)d_in[8], (const float*)d_in[i_l2 + 4] };
    const float* l_rw[2]  = { (const float*)d_in[9], (const float*)d_in[i_l2 + 5] };
    const float* w7 = (const float*)d_in[i_pp + 0];
    const float* b7 = (const float*)d_in[i_pp + 1];
    const float* w5 = (const float*)d_in[i_pp + 2];
    const float* b5 = (const float*)d_in[i_pp + 3];
    const float* w3 = (const float*)d_in[i_pp + 4];
    const float* b3 = (const float*)d_in[i_pp + 5];
    const float* ng   = (const float*)d_in[22];
    const float* nbv  = (const float*)d_in[23];
    const float* fc2w = (const float*)d_in[24];
    const float* fc2b = (const float*)d_in[25];
    float* out = (float*)d_out;

    char* Wb = (char*)d_ws;
    size_t off = 0;
    auto allocB = [&](size_t bytes) { void* p = Wb + off; off = (off + bytes + 255) & ~(size_t)255; return p; };

    float* SEQ   = (float*)allocB((size_t)NSEQ * 512 * 4);
    float* XP    = (float*)allocB((size_t)LPAD * 512 * 4);
    u16*   XPh   = (u16*)  allocB((size_t)LPAD * 512 * 2);
    u16*   QKVh  = (u16*)  allocB((size_t)LPAD * 1536 * 2);
    float* QLKL  = (float*)allocB((size_t)262144 * 4);
    float* QL = QLKL, *KL = QLKL + 131072;
    u16*   QLKLh = (u16*)  allocB((size_t)262144 * 2);
    u16*   QLh = QLKLh, *KLh = QLKLh + 131072;
    float* A2   = (float*)allocB(524288 * 4);
    float* Zf0  = (float*)allocB(524288 * 4);
    float* Zf1  = (float*)allocB(524288 * 4);
    float* XZf  = (float*)allocB(524288 * 4);
    float* W2b  = (float*)allocB(524288 * 4);
    float* W3b  = (float*)allocB(524288 * 4);
    float* A3V  = (float*)allocB(131072 * 4);
    float* ZMATf= (float*)allocB(131072 * 4);
    u16*   ZMATt= (u16*)  allocB(131072 * 2);
    u16*   Vt   = (u16*)  allocB((size_t)8 * 64 * LPAD * 2);
    u16*   fc1wt= (u16*)  allocB(524288 * 2);
    u16*   qkvwt= (u16*)  allocB(786432 * 2);
    u16*   outwt= (u16*)  allocB(262144 * 2);
    float* W49  = (float*)allocB(49 * 512 * 4);
    float* BSUM = (float*)allocB(512 * 4);
    float* SCAL = (float*)allocB(16);
    void*  U1   = allocB((size_t)LPAD * 512 * 4);
    u16*   hbf  = (u16*)U1;
    float* OUT  = (float*)U1;
    float* SEQ2 = OUT;
    size_t fixed = off;

    size_t scB_b = (size_t)8 * 256 * LPAD * 4;
    size_t phB_b = (size_t)8 * 256 * LPAD * 2;
    bool batched = ws_size >= fixed + scB_b + phB_b;
    float* SC; u16* Ph;
    if (batched) {
        SC = (float*)(Wb + fixed);
        Ph = (u16*)(Wb + fixed + scB_b);
    } else {
        SC = (float*)(Wb + fixed);
        Ph = (u16*)(Wb + fixed + (size_t)256 * LPAD * 4);
    }
    u16* OUTh = (u16*)SC;   // alias: SC dead when OUTh materialized

    auto mgemm = [&](const u16* A, int lda, long sA, const u16* Bt, int ldb, long sB,
                     void* C, int ldc, long sC, int M, int N, int K,
                     const float* bias, const float* resid, int ldr,
                     int relu, int qscale, int obf16, int nbatch, int ksplit, int atomic) {
        dim3 grid((N + 127) / 128, (M + 127) / 128, nbatch * ksplit);
        gemm_mfma<<<grid, 256, 0, stream>>>(A, lda, sA, Bt, ldb, sB, C, ldc, sC,
            M, N, K, ksplit, bias, resid, ldr, relu, qscale, obf16, atomic);
    };
    auto fgemm = [&](const float* A, int lda, long sA, const float* B, int ldb, long sB,
                     float* C, int ldc, long sC, int M, int N, int K,
                     float alpha, float diagc, const float* bias,
                     const float* resid, int ldr, long sR, float rescoef,
                     int btrans, int nbatch) {
        dim3 grid(N / 64, (M + 63) / 64, nbatch);
        gemm_big<<<grid, 256, 0, stream>>>(A, lda, sA, B, ldb, sB, C, ldc, sC, M, N, K,
            alpha, diagc, bias, resid, ldr, sR, rescoef, btrans);
    };

    // ---- prologue
    cast_bf16<<<(NPIX * 1024 / 4 + 255) / 256, 256, 0, stream>>>(h, hbf, NPIX * 1024);
    castT<<<(524288 + 255) / 256, 256, 0, stream>>>(fc1_w, fc1wt, 1024, 512, 1);
    mgemm(hbf, 1024, 0, fc1wt, 1024, 0, SEQ + 512, 512, 0, NPIX, 512, 1024,
          fc1_b, nullptr, 0, 1, 0, 0, 1, 1, 0);
    copy512<<<2, 256, 0, stream>>>(SEQ, cls);
    zerok<<<(PADT * 512 + 255) / 256, 256, 0, stream>>>(XP, PADT * 512);
    zerok<<<(PADT * 256 + 255) / 256, 256, 0, stream>>>((float*)XPh, PADT * 256);
    ppeg_combine<<<(49 * 512 + 255) / 256, 256, 0, stream>>>(w7, w5, w3, b7, b5, b3, W49, BSUM);

    for (int layer = 0; layer < 2; layer++) {
        const float* curSEQ = (layer == 0) ? SEQ : SEQ2;
        ln_kernel<<<(NSEQ + 3) / 4, 256, 0, stream>>>(curSEQ, XP + (size_t)PADT * 512,
            XPh + (size_t)PADT * 512, l_g[layer], l_b[layer], NSEQ);
        castT<<<(786432 + 255) / 256, 256, 0, stream>>>(l_qkv[layer], qkvwt, 512, 1536, 1);
        mgemm(XPh, 512, 0, qkvwt, 512, 0, QKVh, 1536, 0, LPAD, 1536, 512,
              nullptr, nullptr, 0, 0, 1, 1, 1, 1, 0);
        landmarks_kernel<<<dim3(256, 8), 64, 0, stream>>>(QKVh, QL, KL, QLh, KLh);
        // a2 = softmax(ql @ kl^T)  (fp32)
        fgemm(QL, 64, 16384, KL, 64, 16384, A2, 256, 65536, 256, 256, 64,
              1.f, 0.f, nullptr, nullptr, 0, 0, 0.f, 1, 8);
        softmax_a2<<<512, 256, 0, stream>>>(A2, 2048);
        zero2k<<<1, 1, 0, stream>>>(SCAL);
        a2norms_kernel<<<8, 256, 0, stream>>>(A2, SCAL);
        z0_kernel<<<dim3(256, 8), 256, 0, stream>>>(A2, SCAL, Zf0);

        // Newton-Schulz: 6 fp32 iterations (round-3 proven config)
        float* zc = Zf0; float* zn = Zf1;
        for (int it = 0; it < 6; it++) {
            fgemm(A2, 256, 65536, zc, 256, 65536, XZf, 256, 65536, 256, 256, 256,
                  1.f, 0.f, nullptr, nullptr, 0, 0, 0.f, 0, 8);
            fgemm(XZf, 256, 65536, XZf, 256, 65536, W2b, 256, 65536, 256, 256, 256,
                  1.f, 15.f, nullptr, XZf, 256, 65536, -7.f, 0, 8);
            fgemm(XZf, 256, 65536, W2b, 256, 65536, W3b, 256, 65536, 256, 256, 256,
                  -1.f, 13.f, nullptr, nullptr, 0, 0, 0.f, 0, 8);
            fgemm(zc, 256, 65536, W3b, 256, 65536, zn, 256, 65536, 256, 256, 256,
                  0.25f, 0.f, nullptr, nullptr, 0, 0, 0.f, 0, 8);
            float* t = zc; zc = zn; zn = t;
        }
        float* zfin = zc;

        // a3v = softmax(ql @ k^T) @ v  via MFMA
        vtrans<<<dim3(160, 8), 256, 0, stream>>>(QKVh, Vt);
        zerok<<<512, 256, 0, stream>>>(A3V, 131072);
        if (batched) {
            mgemm(QLh, 64, 16384, QKVh + 512, 1536, 64, SC, LPAD, (long)256 * LPAD,
                  256, LPAD, 64, nullptr, nullptr, 0, 0, 0, 0, 8, 1, 0);
            row_softmax_bf16<<<2048, 256, 0, stream>>>(SC, Ph, LPAD);
            mgemm(Ph, LPAD, (long)256 * LPAD, Vt, LPAD, (long)64 * LPAD, A3V, 64, 16384,
                  256, 64, LPAD, nullptr, nullptr, 0, 0, 0, 0, 8, 40, 1);
        } else {
            for (int hh = 0; hh < 8; hh++) {
                mgemm(QLh + (size_t)hh * 16384, 64, 0, QKVh + 512 + hh * 64, 1536, 0,
                      SC, LPAD, 0, 256, LPAD, 64, nullptr, nullptr, 0, 0, 0, 0, 1, 1, 0);
                row_softmax_bf16<<<256, 256, 0, stream>>>(SC, Ph, LPAD);
                mgemm(Ph, LPAD, 0, Vt + (size_t)hh * 64 * LPAD, LPAD, 0,
                      A3V + (size_t)hh * 16384, 64, 0, 256, 64, LPAD,
                      nullptr, nullptr, 0, 0, 0, 0, 1, 40, 1);
            }
        }
        // ZMAT = pinv(a2) @ a3v  (fp32)
        fgemm(zfin, 256, 65536, A3V, 64, 16384, ZMATf, 64, 16384, 256, 64, 256,
              1.f, 0.f, nullptr, nullptr, 0, 0, 0.f, 0, 8);

        if (layer == 0) {
            // Z^T bf16 for the fused a1 chain
            castT<<<(131072 + 255) / 256, 256, 0, stream>>>(ZMATf, ZMATt, 256, 64, 8);
            // fused scores+softmax+PZ: one launch, no SC/Ph traffic
            a1z_fused<<<dim3((NSEQ + 63) / 64, 8), 256, 0, stream>>>(
                QKVh, KLh, ZMATt, OUT, PADT);
            conv_res_t<<<(NSEQ + 15) / 16, 256, 0, stream>>>(QKVh, OUT, l_rw[0], PADT, NSEQ);
            cast_bf16<<<(NSEQ * 512 / 4 + 255) / 256, 256, 0, stream>>>(
                OUT + (size_t)PADT * 512, OUTh, NSEQ * 512);
            castT<<<(262144 + 255) / 256, 256, 0, stream>>>(l_ow[0], outwt, 512, 512, 1);
            mgemm(OUTh, 512, 0, outwt, 512, 0, SEQ, 512, 0, NSEQ, 512, 512,
                  l_ob[0], XP + (size_t)PADT * 512, 512, 0, 0, 0, 1, 1, 0);
            // PPEG
            ppeg_fast<<<dim3(10000, 2), 256, 0, stream>>>(SEQ, SEQ2, W49, BSUM);
            copy512<<<2, 256, 0, stream>>>(SEQ2, SEQ);
        } else {
            a1z_single<<<8, 256, 0, stream>>>(QKVh, KL, ZMATf, OUT, PADT);
            conv_res<<<2, 256, 0, stream>>>(QKVh, OUT, l_rw[1], PADT, 1);
            fgemm(OUT + (size_t)PADT * 512, 512, 0, l_ow[1], 512, 0, SEQ, 512, 0,
                  1, 512, 512, 1.f, 0.f, l_ob[1],
                  XP + (size_t)PADT * 512, 512, 0, 1.f, 0, 1);
        }
    }
    final_kernel<<<1, 64, 0, stream>>>(SEQ, ng, nbv, fc2w, fc2b, out);
    (void)n_in; (void)out_size;
}